// Round 3
// baseline (772.070 us; speedup 1.0000x reference)
//
#include <hip/hip_runtime.h>

// Problem constants
#define NB 4
#define NN 256
#define ND 256
#define NL 128
#define NK 256
static constexpr float GAMMA_C = 1e-4f;
static constexpr float ETA_C = 1.0f;

typedef unsigned int u32;

__device__ __forceinline__ u32 pk2bf(float lo, float hi) {
    u32 a = __float_as_uint(lo), b = __float_as_uint(hi);
    a = (a + 0x7FFFu + ((a >> 16) & 1u)) >> 16;   // RNE
    b = (b + 0x7FFFu + ((b >> 16) & 1u)) >> 16;
    return a | (b << 16);
}
__device__ __forceinline__ float bf2f(u32 v) { return __uint_as_float(v << 16); }

// ---------------------------------------------------------------------------
// Generic small GEMM: C[M,Nc] = act(A[M,K] @ W[K,Nc] + bias[col] + addm[row%256,col])
// ---------------------------------------------------------------------------
__global__ __launch_bounds__(256) void gemm64(
    const float* __restrict__ A, const float* __restrict__ W,
    const float* __restrict__ bias, const float* __restrict__ addm,
    float* __restrict__ C, int M, int Kd, int Nc, int relu_act)
{
    __shared__ __align__(16) float As[16][68];
    __shared__ __align__(16) float Ws[16][64];
    int t = threadIdx.x;
    int r0 = blockIdx.x * 64, c0 = blockIdx.y * 64;
    int ty = t >> 4, tx = t & 15;
    float acc[4][4] = {};
    for (int kc = 0; kc < Kd; kc += 16) {
        __syncthreads();
        #pragma unroll
        for (int q = 0; q < 4; ++q) {
            int f = q * 256 + t;
            int row = f >> 4, kk = f & 15;
            As[kk][row] = A[(r0 + row) * Kd + kc + kk];
        }
        #pragma unroll
        for (int q = 0; q < 4; ++q) {
            int f = q * 256 + t;
            int kk = f >> 6, col = f & 63;
            Ws[kk][col] = W[(kc + kk) * Nc + c0 + col];
        }
        __syncthreads();
        #pragma unroll
        for (int kk = 0; kk < 16; ++kk) {
            float4 av = *(const float4*)&As[kk][ty * 4];
            float4 bv = *(const float4*)&Ws[kk][tx * 4];
            float a[4] = {av.x, av.y, av.z, av.w};
            float b[4] = {bv.x, bv.y, bv.z, bv.w};
            #pragma unroll
            for (int i = 0; i < 4; ++i)
                #pragma unroll
                for (int j = 0; j < 4; ++j)
                    acc[i][j] += a[i] * b[j];
        }
    }
    #pragma unroll
    for (int i = 0; i < 4; ++i) {
        int row = r0 + ty * 4 + i;
        #pragma unroll
        for (int j = 0; j < 4; ++j) {
            int col = c0 + tx * 4 + j;
            float v = acc[i][j];
            if (bias) v += bias[col];
            if (addm) v += addm[(row & 255) * Nc + col];
            if (relu_act) v = fmaxf(v, 0.f);
            C[row * Nc + col] = v;
        }
    }
}

// ---------------------------------------------------------------------------
// Graph learning: per (b,i) row -> soft_adj, adj2, loss partials
// ---------------------------------------------------------------------------
__global__ __launch_bounds__(256) void soft_adj_kernel(
    const float* __restrict__ xhat, const float* __restrict__ adj,
    const int* __restrict__ box_num, const float* __restrict__ learn_w,
    float* __restrict__ soft_out, float* __restrict__ adj2,
    float* __restrict__ rowP1, float* __restrict__ rowP2)
{
    __shared__ __align__(16) float xs[NL];
    __shared__ __align__(16) float lw[NL];
    __shared__ float red[256];
    int bi = blockIdx.x;            // b*256 + i
    int b = bi >> 8, i = bi & 255;
    int j = threadIdx.x;
    if (j < NL) { xs[j] = xhat[bi * NL + j]; lw[j] = learn_w[j]; }
    __syncthreads();
    float sumw = 0.f;
    for (int d = 0; d < NL; ++d) sumw += lw[d];
    float s1 = 0.f, s2 = 0.f;
    const float* xj = &xhat[(b * 256 + j) * NL];
    #pragma unroll 4
    for (int d = 0; d < NL; d += 4) {
        float4 a = *(const float4*)&xs[d];
        float4 bb = *(const float4*)&xj[d];
        float d0 = a.x - bb.x, d1 = a.y - bb.y, d2 = a.z - bb.z, d3 = a.w - bb.w;
        s1 += fabsf(d0) * lw[d] + fabsf(d1) * lw[d + 1] + fabsf(d2) * lw[d + 2] + fabsf(d3) * lw[d + 3];
        s2 += d0 * d0 + d1 * d1 + d2 * d2 + d3 * d3;
    }
    int bn = box_num[b];
    float maskv = (i < bn && j < bn) ? 0.f : -1.f;
    float out = s1 + maskv * sumw;
    out = (out >= 0.f) ? out : 0.01f * out;     // leaky_relu slope 0.01
    float pn = sqrtf(s2 + 1e-12f);
    red[j] = out; __syncthreads();
    for (int s = 128; s > 0; s >>= 1) { if (j < s) red[j] = fmaxf(red[j], red[j + s]); __syncthreads(); }
    float m = red[0]; __syncthreads();
    float aij = adj[bi * 256 + j];
    float e = expf(out - m) * aij;
    red[j] = e; __syncthreads();
    for (int s = 128; s > 0; s >>= 1) { if (j < s) red[j] += red[j + s]; __syncthreads(); }
    float S = red[0]; __syncthreads();
    float soft = e / S + 1e-10f;
    soft_out[bi * 256 + j] = soft;
    adj2[bi * 256 + j] = aij * soft;
    float p1 = expf(soft + ETA_C * pn);
    float p2 = soft * soft;
    red[j] = p1; __syncthreads();
    for (int s = 128; s > 0; s >>= 1) { if (j < s) red[j] += red[j + s]; __syncthreads(); }
    if (j == 0) rowP1[bi] = red[0];
    __syncthreads();
    red[j] = p2; __syncthreads();
    for (int s = 128; s > 0; s >>= 1) { if (j < s) red[j] += red[j + s]; __syncthreads(); }
    if (j == 0) rowP2[bi] = red[0];
}

__global__ __launch_bounds__(256) void gl_loss_kernel(
    const float* __restrict__ rowP1, const float* __restrict__ rowP2,
    const int* __restrict__ box_num, float* __restrict__ out)
{
    __shared__ float r1[256], r2[256];
    int b = blockIdx.x, t = threadIdx.x;
    r1[t] = rowP1[b * 256 + t];
    r2[t] = rowP2[b * 256 + t];
    __syncthreads();
    for (int s = 128; s > 0; s >>= 1) { if (t < s) { r1[t] += r1[t + s]; r2[t] += r2[t + s]; } __syncthreads(); }
    if (t == 0) {
        float bn = (float)box_num[b];
        out[b] = r1[0] / (bn * bn) + GAMMA_C * sqrtf(r2[0]);
    }
}

// ---------------------------------------------------------------------------
// Pass 1 (tiers A/B): per (b, 8i, 8j) tile: H0 -> alpha1 (f32 or bf16), AH0 partials
// ---------------------------------------------------------------------------
template<int MODE>   // 0 = f32 alpha1, 1 = bf16 alpha1
__global__ __launch_bounds__(256) void pass1(
    const float* __restrict__ rel, const float* __restrict__ Wat,
    const float* __restrict__ b_alpha, const float* __restrict__ xi0,
    const float* __restrict__ xj0b, const float* __restrict__ adj2,
    const float* __restrict__ w_alpha0,
    void* __restrict__ alpha1, float* __restrict__ ahpart)
{
    __shared__ float xi_s[8][257];
    __shared__ float xj_s[8][257];
    __shared__ __align__(16) float wat_s[6][256];
    __shared__ __align__(16) float ba_s[256];
    __shared__ __align__(16) float rel_s[6][64];
    __shared__ __align__(16) float adj_s[64];
    __shared__ __align__(16) float hs[16][64];
    __shared__ __align__(16) float ws_s[16][256];
    __shared__ float ah_s[8][257];

    int t = threadIdx.x;
    int jt = blockIdx.x, it = blockIdx.y, b = blockIdx.z;
    int i0 = it * 8, j0 = jt * 8;

    #pragma unroll
    for (int q = 0; q < 8; ++q) {
        xi_s[q][t] = xi0[(b * 256 + i0 + q) * 256 + t];
        xj_s[q][t] = xj0b[(b * 256 + j0 + q) * 256 + t];
    }
    #pragma unroll
    for (int q = 0; q < 6; ++q) wat_s[q][t] = Wat[q * 256 + t];
    ba_s[t] = b_alpha[t];
    for (int e = t; e < 384; e += 256) {
        int ii = e / 48, rem = e % 48;
        int jj = rem / 6, c = rem % 6;
        rel_s[c][ii * 8 + jj] = rel[((b * 256 + i0 + ii) * 256 + j0 + jj) * 6 + c];
    }
    if (t < 64) adj_s[t] = adj2[(b * 256 + i0 + (t >> 3)) * 256 + j0 + (t & 7)];
    for (int e = t; e < 8 * 257; e += 256) (&ah_s[0][0])[e] = 0.f;

    float acc[8][8] = {};
    int rg = t >> 5, cg = t & 31;
    int lane = t & 63, wv = t >> 6;
    int ii_l = lane >> 3, jj_l = lane & 7;

    for (int c = 0; c < 16; ++c) {
        __syncthreads();
        #pragma unroll
        for (int p = 0; p < 4; ++p) {
            int klocal = wv + p * 4;
            int kg = c * 16 + klocal;
            float a = ba_s[kg];
            #pragma unroll
            for (int cc = 0; cc < 6; ++cc) a += rel_s[cc][lane] * wat_s[cc][kg];
            float h = xi_s[ii_l][kg] + xj_s[jj_l][kg] + a;
            h = fmaxf(h, 0.f);
            hs[klocal][lane] = h;
            float v = adj_s[lane] * h;
            v += __shfl_xor(v, 1);
            v += __shfl_xor(v, 2);
            v += __shfl_xor(v, 4);
            if (jj_l == 0) ah_s[ii_l][kg] += v;
        }
        #pragma unroll
        for (int q = 0; q < 4; ++q) {
            int f = q * 256 + t;
            int row = f >> 6, col4 = f & 63;
            *(float4*)&ws_s[row][col4 * 4] =
                *(const float4*)&w_alpha0[(c * 16 + row) * 256 + col4 * 4];
        }
        __syncthreads();
        #pragma unroll
        for (int kk = 0; kk < 16; ++kk) {
            float4 a0 = *(const float4*)&hs[kk][rg * 8];
            float4 a1 = *(const float4*)&hs[kk][rg * 8 + 4];
            float4 b0 = *(const float4*)&ws_s[kk][cg * 8];
            float4 b1 = *(const float4*)&ws_s[kk][cg * 8 + 4];
            float av[8] = {a0.x, a0.y, a0.z, a0.w, a1.x, a1.y, a1.z, a1.w};
            float bv[8] = {b0.x, b0.y, b0.z, b0.w, b1.x, b1.y, b1.z, b1.w};
            #pragma unroll
            for (int x = 0; x < 8; ++x)
                #pragma unroll
                for (int y = 0; y < 8; ++y)
                    acc[x][y] += av[x] * bv[y];
        }
    }
    __syncthreads();
    // alpha1 = relu(acc); note: for pair row r = rg*8+x, ii = rg, jj = x
    #pragma unroll
    for (int x = 0; x < 8; ++x) {
        int addr = ((b * 256 + i0 + rg) * 256 + j0 + x) * 256 + cg * 8;
        float4 o0, o1;
        o0.x = fmaxf(acc[x][0], 0.f); o0.y = fmaxf(acc[x][1], 0.f);
        o0.z = fmaxf(acc[x][2], 0.f); o0.w = fmaxf(acc[x][3], 0.f);
        o1.x = fmaxf(acc[x][4], 0.f); o1.y = fmaxf(acc[x][5], 0.f);
        o1.z = fmaxf(acc[x][6], 0.f); o1.w = fmaxf(acc[x][7], 0.f);
        if (MODE == 0) {
            float* A = (float*)alpha1;
            *(float4*)&A[addr] = o0;
            *(float4*)&A[addr + 4] = o1;
        } else {
            u32* A = (u32*)alpha1;
            uint4 pk;
            pk.x = pk2bf(o0.x, o0.y); pk.y = pk2bf(o0.z, o0.w);
            pk.z = pk2bf(o1.x, o1.y); pk.w = pk2bf(o1.z, o1.w);
            *(uint4*)&A[addr >> 1] = pk;
        }
    }
    #pragma unroll
    for (int q = 0; q < 8; ++q)
        ahpart[(((jt * 4 + b) * 32 + it) * 8 + q) * 256 + t] = ah_s[q][t];
}

__global__ __launch_bounds__(256) void reduce_ah(
    const float* __restrict__ part, float* __restrict__ AH0)
{
    int bi = blockIdx.x;
    int b = bi >> 8, i = bi & 255;
    int it = i >> 3, ii = i & 7;
    int t = threadIdx.x;
    float s = 0.f;
    for (int jt = 0; jt < 32; ++jt)
        s += part[(((jt * 4 + b) * 32 + it) * 8 + ii) * 256 + t];
    AH0[bi * 256 + t] = s;
}

// ---------------------------------------------------------------------------
// Pass 2 (tiers A/B): stream alpha1, accumulate AH1
// ---------------------------------------------------------------------------
template<int MODE>
__global__ __launch_bounds__(256) void pass2(
    const void* __restrict__ alpha1, const float* __restrict__ xi1,
    const float* __restrict__ xj1b, const float* __restrict__ adj2,
    float* __restrict__ AH1)
{
    __shared__ __align__(16) float partial[4][256];
    int bi = blockIdx.x;
    int b = bi >> 8;
    int t = threadIdx.x;
    int wv = t >> 6, lane = t & 63;
    int k4 = lane * 4;
    float4 xi = *(const float4*)&xi1[bi * 256 + k4];
    float4 acc = {0.f, 0.f, 0.f, 0.f};
    size_t base = (size_t)bi * 65536;
    const float* a2row = &adj2[bi * 256];
    for (int j = wv; j < 256; j += 4) {
        float a2 = a2row[j];
        float4 xj = *(const float4*)&xj1b[(b * 256 + j) * 256 + k4];
        float4 al;
        if (MODE == 0) {
            al = *(const float4*)&((const float*)alpha1)[base + j * 256 + k4];
        } else {
            uint2 q = *(const uint2*)&((const u32*)alpha1)[(base + j * 256 + k4) >> 1];
            al.x = bf2f(q.x & 0xFFFFu); al.y = bf2f(q.x >> 16);
            al.z = bf2f(q.y & 0xFFFFu); al.w = bf2f(q.y >> 16);
        }
        acc.x += a2 * fmaxf(xi.x + xj.x + al.x, 0.f);
        acc.y += a2 * fmaxf(xi.y + xj.y + al.y, 0.f);
        acc.z += a2 * fmaxf(xi.z + xj.z + al.z, 0.f);
        acc.w += a2 * fmaxf(xi.w + xj.w + al.w, 0.f);
    }
    *(float4*)&partial[wv][k4] = acc;
    __syncthreads();
    if (wv == 0) {
        float4 p0 = *(const float4*)&partial[0][k4];
        float4 p1 = *(const float4*)&partial[1][k4];
        float4 p2 = *(const float4*)&partial[2][k4];
        float4 p3 = *(const float4*)&partial[3][k4];
        float4 o;
        o.x = p0.x + p1.x + p2.x + p3.x;
        o.y = p0.y + p1.y + p2.y + p3.y;
        o.z = p0.z + p1.z + p2.z + p3.z;
        o.w = p0.w + p1.w + p2.w + p3.w;
        *(float4*)&AH1[bi * 256 + k4] = o;
    }
}

// ---------------------------------------------------------------------------
// Tier C pass 1: AH0 directly (no alpha1/part). Block = (it, b), thread owns k=t.
// ---------------------------------------------------------------------------
__global__ __launch_bounds__(256) void pass1C(
    const float* __restrict__ rel, const float* __restrict__ Wat,
    const float* __restrict__ b_alpha, const float* __restrict__ xi0,
    const float* __restrict__ xj0b, const float* __restrict__ adj2,
    float* __restrict__ AH0)
{
    __shared__ float xj_s[16][257];
    __shared__ float rel_s[16 * 48];
    __shared__ float adj_sC[128];
    int t = threadIdx.x;
    int it = blockIdx.x, b = blockIdx.y;
    int i0 = it * 8;
    float xiv[8], watv[6];
    #pragma unroll
    for (int ii = 0; ii < 8; ++ii) xiv[ii] = xi0[(b * 256 + i0 + ii) * 256 + t];
    #pragma unroll
    for (int c = 0; c < 6; ++c) watv[c] = Wat[c * 256 + t];
    float bav = b_alpha[t];
    float ah[8] = {};
    for (int jc = 0; jc < 256; jc += 16) {
        __syncthreads();
        #pragma unroll
        for (int q = 0; q < 16; ++q) xj_s[q][t] = xj0b[(b * 256 + jc + q) * 256 + t];
        for (int e = t; e < 768; e += 256) {
            int jj = e / 48, r = e % 48;
            rel_s[e] = rel[((b * 256 + i0 + r / 6) * 256 + jc + jj) * 6 + (r % 6)];
        }
        if (t < 128) adj_sC[t] = adj2[(b * 256 + i0 + (t & 7)) * 256 + jc + (t >> 3)];
        __syncthreads();
        for (int jj = 0; jj < 16; ++jj) {
            float xjv = xj_s[jj][t];
            #pragma unroll
            for (int ii = 0; ii < 8; ++ii) {
                float a = bav;
                #pragma unroll
                for (int c = 0; c < 6; ++c) a += rel_s[jj * 48 + ii * 6 + c] * watv[c];
                float h = fmaxf(xiv[ii] + xjv + a, 0.f);
                ah[ii] += adj_sC[jj * 8 + ii] * h;
            }
        }
    }
    #pragma unroll
    for (int ii = 0; ii < 8; ++ii)
        AH0[(b * 256 + i0 + ii) * 256 + t] = ah[ii];
}

// ---------------------------------------------------------------------------
// Tier C pass 2: recompute H0 tile + alpha1 tile (GEMM) + H1 + AH1, no big buffer.
// Block = (it, b), loops all 32 j-tiles. Thread owns ii=rg, k=cg*8..+7 for AH1.
// ---------------------------------------------------------------------------
__global__ __launch_bounds__(256) void pass2C(
    const float* __restrict__ rel, const float* __restrict__ Wat,
    const float* __restrict__ b_alpha, const float* __restrict__ xi0,
    const float* __restrict__ xj0b, const float* __restrict__ w_alpha0,
    const float* __restrict__ xi1, const float* __restrict__ xj1b,
    const float* __restrict__ adj2, float* __restrict__ AH1)
{
    __shared__ float xi_s[8][257];
    __shared__ float xj_s[8][257];
    __shared__ float xj1_s[8][257];
    __shared__ __align__(16) float wat_s[6][256];
    __shared__ __align__(16) float ba_s[256];
    __shared__ __align__(16) float rel_s[6][64];
    __shared__ __align__(16) float adj_s[64];
    __shared__ __align__(16) float hs[16][64];
    __shared__ __align__(16) float ws_s[16][256];

    int t = threadIdx.x;
    int it = blockIdx.x, b = blockIdx.y;
    int i0 = it * 8;
    int rg = t >> 5, cg = t & 31;
    int lane = t & 63, wv = t >> 6;
    int ii_l = lane >> 3, jj_l = lane & 7;

    #pragma unroll
    for (int q = 0; q < 8; ++q) xi_s[q][t] = xi0[(b * 256 + i0 + q) * 256 + t];
    #pragma unroll
    for (int q = 0; q < 6; ++q) wat_s[q][t] = Wat[q * 256 + t];
    ba_s[t] = b_alpha[t];
    float xi1v[8];
    #pragma unroll
    for (int y = 0; y < 8; ++y) xi1v[y] = xi1[(b * 256 + i0 + rg) * 256 + cg * 8 + y];
    float ah1[8] = {};

    for (int jt = 0; jt < 32; ++jt) {
        int j0 = jt * 8;
        __syncthreads();   // previous iteration done reading xj_s/xj1_s/rel_s/adj_s
        #pragma unroll
        for (int q = 0; q < 8; ++q) {
            xj_s[q][t]  = xj0b[(b * 256 + j0 + q) * 256 + t];
            xj1_s[q][t] = xj1b[(b * 256 + j0 + q) * 256 + t];
        }
        for (int e = t; e < 384; e += 256) {
            int ii = e / 48, rem = e % 48;
            int jj = rem / 6, c = rem % 6;
            rel_s[c][ii * 8 + jj] = rel[((b * 256 + i0 + ii) * 256 + j0 + jj) * 6 + c];
        }
        if (t < 64) adj_s[t] = adj2[(b * 256 + i0 + (t >> 3)) * 256 + j0 + (t & 7)];

        float acc[8][8] = {};
        for (int c = 0; c < 16; ++c) {
            __syncthreads();
            #pragma unroll
            for (int p = 0; p < 4; ++p) {
                int klocal = wv + p * 4;
                int kg = c * 16 + klocal;
                float a = ba_s[kg];
                #pragma unroll
                for (int cc = 0; cc < 6; ++cc) a += rel_s[cc][lane] * wat_s[cc][kg];
                float h = xi_s[ii_l][kg] + xj_s[jj_l][kg] + a;
                hs[klocal][lane] = fmaxf(h, 0.f);
            }
            #pragma unroll
            for (int q = 0; q < 4; ++q) {
                int f = q * 256 + t;
                int row = f >> 6, col4 = f & 63;
                *(float4*)&ws_s[row][col4 * 4] =
                    *(const float4*)&w_alpha0[(c * 16 + row) * 256 + col4 * 4];
            }
            __syncthreads();
            #pragma unroll
            for (int kk = 0; kk < 16; ++kk) {
                float4 a0 = *(const float4*)&hs[kk][rg * 8];
                float4 a1 = *(const float4*)&hs[kk][rg * 8 + 4];
                float4 b0 = *(const float4*)&ws_s[kk][cg * 8];
                float4 b1 = *(const float4*)&ws_s[kk][cg * 8 + 4];
                float av[8] = {a0.x, a0.y, a0.z, a0.w, a1.x, a1.y, a1.z, a1.w};
                float bv[8] = {b0.x, b0.y, b0.z, b0.w, b1.x, b1.y, b1.z, b1.w};
                #pragma unroll
                for (int x = 0; x < 8; ++x)
                    #pragma unroll
                    for (int y = 0; y < 8; ++y)
                        acc[x][y] += av[x] * bv[y];
            }
        }
        // epilogue: pair row r = rg*8+x -> ii = rg, jj = x
        #pragma unroll
        for (int x = 0; x < 8; ++x) {
            float a2 = adj_s[rg * 8 + x];
            #pragma unroll
            for (int y = 0; y < 8; ++y) {
                float al = fmaxf(acc[x][y], 0.f);
                float h1 = fmaxf(xi1v[y] + xj1_s[x][cg * 8 + y] + al, 0.f);
                ah1[y] += a2 * h1;
            }
        }
    }
    #pragma unroll
    for (int y = 0; y < 8; ++y)
        AH1[(b * 256 + i0 + rg) * 256 + cg * 8 + y] = ah1[y];
}

// ---------------------------------------------------------------------------
extern "C" void kernel_launch(void* const* d_in, const int* in_sizes, int n_in,
                              void* d_out, int out_size, void* d_ws, size_t ws_size,
                              hipStream_t stream)
{
    const float* x        = (const float*)d_in[0];
    const float* rel      = (const float*)d_in[1];
    const float* adj      = (const float*)d_in[2];
    const int*   box_num  = (const int*)d_in[3];
    const float* Wat      = (const float*)d_in[4];
    const float* b_alpha  = (const float*)d_in[5];
    const float* W_proj   = (const float*)d_in[6];
    const float* b_proj   = (const float*)d_in[7];
    const float* learn_w  = (const float*)d_in[8];
    const float* w_alpha0 = (const float*)d_in[9];
    const float* w_vi0    = (const float*)d_in[10];
    const float* w_vj0    = (const float*)d_in[11];
    const float* bias_h0  = (const float*)d_in[12];
    const float* w_node0  = (const float*)d_in[13];
    // d_in[14] = l1_w_alpha (unused: layer-1 new_alpha is discarded)
    const float* w_vi1    = (const float*)d_in[15];
    const float* w_vj1    = (const float*)d_in[16];
    const float* bias_h1  = (const float*)d_in[17];
    const float* w_node1  = (const float*)d_in[18];

    // ---- workspace layout: smalls first (shared by all tiers) ----
    float* sm    = (float*)d_ws;
    float* adj2  = sm;                 // 262,144
    float* xhat  = adj2  + 262144;     // 131,072
    float* xi0   = xhat  + 131072;     // 262,144
    float* xj0b  = xi0   + 262144;     // 262,144
    float* AH0   = xj0b  + 262144;     // 262,144
    float* x1    = AH0   + 262144;     // 262,144
    float* xi1   = x1    + 262144;     // 262,144
    float* xj1b  = xi1   + 262144;     // 262,144
    float* AH1   = xj1b  + 262144;     // 262,144
    float* rowP1 = AH1   + 262144;     //   1,024
    float* rowP2 = rowP1 + 1024;       //   1,024
    const size_t SMALLS_F = 2230272;   // floats
    const size_t PART_F   = 8388608;   // floats
    float* part   = sm + SMALLS_F;
    void*  alpha1 = (void*)(sm + SMALLS_F + PART_F);

    const size_t needA = (SMALLS_F + PART_F + 67108864ULL) * 4ULL;         // ~311 MB
    const size_t needB = (SMALLS_F + PART_F) * 4ULL + 67108864ULL * 2ULL;  // ~177 MB
    int tier = (ws_size >= needA) ? 0 : (ws_size >= needB) ? 1 : 2;

    float* out_x2   = (float*)d_out;           // 262,144
    float* out_soft = out_x2 + 262144;         // 262,144
    float* out_gl   = out_soft + 262144;       //       4

    // Phase A: graph learning
    gemm64<<<dim3(16, 2), 256, 0, stream>>>(x, W_proj, b_proj, nullptr, xhat, 1024, 256, 128, 0);
    soft_adj_kernel<<<1024, 256, 0, stream>>>(xhat, adj, box_num, learn_w, out_soft, adj2, rowP1, rowP2);
    gl_loss_kernel<<<4, 256, 0, stream>>>(rowP1, rowP2, box_num, out_gl);

    // Layer 0 projections (bias_h0 folded into xj)
    gemm64<<<dim3(16, 4), 256, 0, stream>>>(x, w_vi0, nullptr, nullptr, xi0, 1024, 256, 256, 0);
    gemm64<<<dim3(16, 4), 256, 0, stream>>>(x, w_vj0, nullptr, bias_h0, xj0b, 1024, 256, 256, 0);

    // Layer 0 heavy pass -> AH0 (+ alpha1 in tiers A/B)
    if (tier == 0) {
        pass1<0><<<dim3(32, 32, 4), 256, 0, stream>>>(rel, Wat, b_alpha, xi0, xj0b, adj2, w_alpha0, alpha1, part);
        reduce_ah<<<1024, 256, 0, stream>>>(part, AH0);
    } else if (tier == 1) {
        pass1<1><<<dim3(32, 32, 4), 256, 0, stream>>>(rel, Wat, b_alpha, xi0, xj0b, adj2, w_alpha0, alpha1, part);
        reduce_ah<<<1024, 256, 0, stream>>>(part, AH0);
    } else {
        pass1C<<<dim3(32, 4), 256, 0, stream>>>(rel, Wat, b_alpha, xi0, xj0b, adj2, AH0);
    }

    // Layer 0 node update + layer 1 projections
    gemm64<<<dim3(16, 4), 256, 0, stream>>>(AH0, w_node0, nullptr, nullptr, x1, 1024, 256, 256, 1);
    gemm64<<<dim3(16, 4), 256, 0, stream>>>(x1, w_vi1, nullptr, nullptr, xi1, 1024, 256, 256, 0);
    gemm64<<<dim3(16, 4), 256, 0, stream>>>(x1, w_vj1, nullptr, bias_h1, xj1b, 1024, 256, 256, 0);

    // Layer 1 -> AH1
    if (tier == 0) {
        pass2<0><<<1024, 256, 0, stream>>>(alpha1, xi1, xj1b, adj2, AH1);
    } else if (tier == 1) {
        pass2<1><<<1024, 256, 0, stream>>>(alpha1, xi1, xj1b, adj2, AH1);
    } else {
        pass2C<<<dim3(32, 4), 256, 0, stream>>>(rel, Wat, b_alpha, xi0, xj0b, w_alpha0, xi1, xj1b, adj2, AH1);
    }

    // Final node update -> x2
    gemm64<<<dim3(16, 4), 256, 0, stream>>>(AH1, w_node1, nullptr, nullptr, out_x2, 1024, 256, 256, 1);
}

// Round 4
// 478.951 us; speedup vs baseline: 1.6120x; 1.6120x over previous
//
#include <hip/hip_runtime.h>

// Problem constants
#define NB 4
#define NN 256
#define ND 256
#define NL 128
#define NK 256
static constexpr float GAMMA_C = 1e-4f;
static constexpr float ETA_C = 1.0f;

typedef unsigned int u32;
typedef __attribute__((ext_vector_type(8))) short bf16x8;
typedef __attribute__((ext_vector_type(4))) float f32x4;

__device__ __forceinline__ u32 rne1(float x) {            // f32 -> bf16 bits (RNE)
    u32 a = __float_as_uint(x);
    return (a + 0x7FFFu + ((a >> 16) & 1u)) >> 16;
}
__device__ __forceinline__ float bf2f(u32 v) { return __uint_as_float(v << 16); }
__device__ __forceinline__ u32 pk2bf(float lo, float hi) { return rne1(lo) | (rne1(hi) << 16); }

// ---------------------------------------------------------------------------
// Generic small GEMM: C[M,Nc] = act(A[M,K] @ W[K,Nc] + bias[col] + addm[row%256,col])
// ---------------------------------------------------------------------------
__global__ __launch_bounds__(256) void gemm64(
    const float* __restrict__ A, const float* __restrict__ W,
    const float* __restrict__ bias, const float* __restrict__ addm,
    float* __restrict__ C, int M, int Kd, int Nc, int relu_act)
{
    __shared__ __align__(16) float As[16][68];
    __shared__ __align__(16) float Ws[16][64];
    int t = threadIdx.x;
    int r0 = blockIdx.x * 64, c0 = blockIdx.y * 64;
    int ty = t >> 4, tx = t & 15;
    float acc[4][4] = {};
    for (int kc = 0; kc < Kd; kc += 16) {
        __syncthreads();
        #pragma unroll
        for (int q = 0; q < 4; ++q) {
            int f = q * 256 + t;
            int row = f >> 4, kk = f & 15;
            As[kk][row] = A[(r0 + row) * Kd + kc + kk];
        }
        #pragma unroll
        for (int q = 0; q < 4; ++q) {
            int f = q * 256 + t;
            int kk = f >> 6, col = f & 63;
            Ws[kk][col] = W[(kc + kk) * Nc + c0 + col];
        }
        __syncthreads();
        #pragma unroll
        for (int kk = 0; kk < 16; ++kk) {
            float4 av = *(const float4*)&As[kk][ty * 4];
            float4 bv = *(const float4*)&Ws[kk][tx * 4];
            float a[4] = {av.x, av.y, av.z, av.w};
            float b[4] = {bv.x, bv.y, bv.z, bv.w};
            #pragma unroll
            for (int i = 0; i < 4; ++i)
                #pragma unroll
                for (int j = 0; j < 4; ++j)
                    acc[i][j] += a[i] * b[j];
        }
    }
    #pragma unroll
    for (int i = 0; i < 4; ++i) {
        int row = r0 + ty * 4 + i;
        #pragma unroll
        for (int j = 0; j < 4; ++j) {
            int col = c0 + tx * 4 + j;
            float v = acc[i][j];
            if (bias) v += bias[col];
            if (addm) v += addm[(row & 255) * Nc + col];
            if (relu_act) v = fmaxf(v, 0.f);
            C[row * Nc + col] = v;
        }
    }
}

// ---------------------------------------------------------------------------
// Graph learning: per (b,i) row -> soft_adj, adj2, loss partials
// ---------------------------------------------------------------------------
__global__ __launch_bounds__(256) void soft_adj_kernel(
    const float* __restrict__ xhat, const float* __restrict__ adj,
    const int* __restrict__ box_num, const float* __restrict__ learn_w,
    float* __restrict__ soft_out, float* __restrict__ adj2,
    float* __restrict__ rowP1, float* __restrict__ rowP2)
{
    __shared__ __align__(16) float xs[NL];
    __shared__ __align__(16) float lw[NL];
    __shared__ float red[256];
    int bi = blockIdx.x;            // b*256 + i
    int b = bi >> 8, i = bi & 255;
    int j = threadIdx.x;
    if (j < NL) { xs[j] = xhat[bi * NL + j]; lw[j] = learn_w[j]; }
    __syncthreads();
    float sumw = 0.f;
    for (int d = 0; d < NL; ++d) sumw += lw[d];
    float s1 = 0.f, s2 = 0.f;
    const float* xj = &xhat[(b * 256 + j) * NL];
    #pragma unroll 4
    for (int d = 0; d < NL; d += 4) {
        float4 a = *(const float4*)&xs[d];
        float4 bb = *(const float4*)&xj[d];
        float d0 = a.x - bb.x, d1 = a.y - bb.y, d2 = a.z - bb.z, d3 = a.w - bb.w;
        s1 += fabsf(d0) * lw[d] + fabsf(d1) * lw[d + 1] + fabsf(d2) * lw[d + 2] + fabsf(d3) * lw[d + 3];
        s2 += d0 * d0 + d1 * d1 + d2 * d2 + d3 * d3;
    }
    int bn = box_num[b];
    float maskv = (i < bn && j < bn) ? 0.f : -1.f;
    float out = s1 + maskv * sumw;
    out = (out >= 0.f) ? out : 0.01f * out;     // leaky_relu slope 0.01
    float pn = sqrtf(s2 + 1e-12f);
    red[j] = out; __syncthreads();
    for (int s = 128; s > 0; s >>= 1) { if (j < s) red[j] = fmaxf(red[j], red[j + s]); __syncthreads(); }
    float m = red[0]; __syncthreads();
    float aij = adj[bi * 256 + j];
    float e = expf(out - m) * aij;
    red[j] = e; __syncthreads();
    for (int s = 128; s > 0; s >>= 1) { if (j < s) red[j] += red[j + s]; __syncthreads(); }
    float S = red[0]; __syncthreads();
    float soft = e / S + 1e-10f;
    soft_out[bi * 256 + j] = soft;
    adj2[bi * 256 + j] = aij * soft;
    float p1 = expf(soft + ETA_C * pn);
    float p2 = soft * soft;
    red[j] = p1; __syncthreads();
    for (int s = 128; s > 0; s >>= 1) { if (j < s) red[j] += red[j + s]; __syncthreads(); }
    if (j == 0) rowP1[bi] = red[0];
    __syncthreads();
    red[j] = p2; __syncthreads();
    for (int s = 128; s > 0; s >>= 1) { if (j < s) red[j] += red[j + s]; __syncthreads(); }
    if (j == 0) rowP2[bi] = red[0];
}

__global__ __launch_bounds__(256) void gl_loss_kernel(
    const float* __restrict__ rowP1, const float* __restrict__ rowP2,
    const int* __restrict__ box_num, float* __restrict__ out)
{
    __shared__ float r1[256], r2[256];
    int b = blockIdx.x, t = threadIdx.x;
    r1[t] = rowP1[b * 256 + t];
    r2[t] = rowP2[b * 256 + t];
    __syncthreads();
    for (int s = 128; s > 0; s >>= 1) { if (t < s) { r1[t] += r1[t + s]; r2[t] += r2[t + s]; } __syncthreads(); }
    if (t == 0) {
        float bn = (float)box_num[b];
        out[b] = r1[0] / (bn * bn) + GAMMA_C * sqrtf(r2[0]);
    }
}

// ---------------------------------------------------------------------------
// W prep: split w_alpha0 (256x256, k-major) into hi/lo bf16, packed u32 pairs,
// laid out exactly in the per-kstep staging order:
//   wTp[hl][c(8)][kgl(4)][n(256)][q(4)]  with u32 q packing k = c*32+kgl*8+2q, +1
// 32 blocks (c,kgl) x 256 threads (n).
// ---------------------------------------------------------------------------
__global__ __launch_bounds__(256) void wprep(
    const float* __restrict__ w_alpha0, u32* __restrict__ wTp)
{
    int c = blockIdx.x >> 2, kgl = blockIdx.x & 3;
    int n = threadIdx.x;
    #pragma unroll
    for (int q = 0; q < 4; ++q) {
        int k = c * 32 + kgl * 8 + 2 * q;
        float w0 = w_alpha0[k * 256 + n];
        float w1 = w_alpha0[(k + 1) * 256 + n];
        u32 h0 = rne1(w0), h1 = rne1(w1);
        float l0 = w0 - bf2f(h0), l1 = w1 - bf2f(h1);
        wTp[(((0 * 8 + c) * 4 + kgl) * 256 + n) * 4 + q] = h0 | (rne1(w1) << 16 >> 16 << 16);  // placeholder avoided below
        wTp[(((0 * 8 + c) * 4 + kgl) * 256 + n) * 4 + q] = h0 | (h1 << 16);
        wTp[(((1 * 8 + c) * 4 + kgl) * 256 + n) * 4 + q] = rne1(l0) | (rne1(l1) << 16);
    }
}

// ---------------------------------------------------------------------------
// Pass 1 (MFMA): per (b, 8i, 8j) tile: H0 on-the-fly (f32) -> split hi/lo bf16
// -> alpha1 = relu(H0 @ w_alpha0) via bf16x3 MFMA (error ~2^-16, f32-like),
// stored as packed bf16. AH0 partials f32 as before.
// 4 waves; wave wv owns k-subgroup wv (H-compute) and n-range wv*64 (GEMM).
// ---------------------------------------------------------------------------
__global__ __launch_bounds__(256) void pass1M(
    const float* __restrict__ rel, const float* __restrict__ Wat,
    const float* __restrict__ b_alpha, const float* __restrict__ xi0,
    const float* __restrict__ xj0b, const float* __restrict__ adj2,
    const u32* __restrict__ wTp,
    u32* __restrict__ alpha1, float* __restrict__ ahpart)
{
    __shared__ __align__(16) float watb_s[256][8];   // {Wat[0..5][k], b_alpha[k], 0}
    __shared__ float ah_s[8][260];
    __shared__ __align__(16) u32 hsA[2][4][64][4];   // [hl][kgl][m][4u32]
    __shared__ __align__(16) char wbraw[33792];      // wb[2][4][256][4] u32 / st[32][260] f32
    u32 (*wb)[4][256][4] = (u32(*)[4][256][4])wbraw;
    float (*st)[260] = (float(*)[260])wbraw;

    int t = threadIdx.x;
    int jt = blockIdx.x, it = blockIdx.y, b = blockIdx.z;
    int i0 = it * 8, j0 = jt * 8;
    int m = t & 63, wv = t >> 6;       // lane == m; wave id wv
    int ii = m >> 3, jj = m & 7;
    int l4 = m >> 4, l16 = m & 15;

    // block-start staging
    #pragma unroll
    for (int q = 0; q < 8; ++q)
        watb_s[t][q] = (q < 6) ? Wat[q * 256 + t] : (q == 6 ? b_alpha[t] : 0.f);
    for (int e = t; e < 8 * 260; e += 256) (&ah_s[0][0])[e] = 0.f;
    float relv2[8];
    #pragma unroll
    for (int c = 0; c < 6; ++c)
        relv2[c] = rel[((b * 256 + i0 + ii) * 256 + j0 + jj) * 6 + c];
    relv2[6] = 1.f; relv2[7] = 0.f;
    float adjv = adj2[(b * 256 + i0 + ii) * 256 + j0 + jj];

    f32x4 acc[4][4];
    #pragma unroll
    for (int a = 0; a < 4; ++a)
        #pragma unroll
        for (int c = 0; c < 4; ++c)
            acc[a][c] = (f32x4){0.f, 0.f, 0.f, 0.f};

    __syncthreads();

    for (int c = 0; c < 8; ++c) {
        // (a) issue W-stage global loads early (latency hides under H-compute)
        uint4 wreg[2][4];
        #pragma unroll
        for (int hl = 0; hl < 2; ++hl)
            #pragma unroll
            for (int q4 = 0; q4 < 4; ++q4) {
                int f = q4 * 256 + t;
                wreg[hl][q4] = *(const uint4*)&wTp[(hl * 8 + c) * 4096 + f * 4];
            }

        // (b) H0 chunk: thread computes h(m, k) for k = c*32 + wv*8 + 0..7
        int kb = c * 32 + wv * 8;
        float xiarr[8], xjarr[8];
        {
            const float4* xa = (const float4*)&xi0[(b * 256 + i0 + ii) * 256 + kb];
            float4 x0 = xa[0], x1 = xa[1];
            xiarr[0]=x0.x; xiarr[1]=x0.y; xiarr[2]=x0.z; xiarr[3]=x0.w;
            xiarr[4]=x1.x; xiarr[5]=x1.y; xiarr[6]=x1.z; xiarr[7]=x1.w;
            const float4* xb = (const float4*)&xj0b[(b * 256 + j0 + jj) * 256 + kb];
            float4 y0 = xb[0], y1 = xb[1];
            xjarr[0]=y0.x; xjarr[1]=y0.y; xjarr[2]=y0.z; xjarr[3]=y0.w;
            xjarr[4]=y1.x; xjarr[5]=y1.y; xjarr[6]=y1.z; xjarr[7]=y1.w;
        }
        float h[8];
        #pragma unroll
        for (int i = 0; i < 8; ++i) {
            int k = kb + i;
            float4 wa = *(const float4*)&watb_s[k][0];   // broadcast (uniform addr)
            float4 wc = *(const float4*)&watb_s[k][4];
            float a = relv2[0]*wa.x + relv2[1]*wa.y + relv2[2]*wa.z + relv2[3]*wa.w
                    + relv2[4]*wc.x + relv2[5]*wc.y + wc.z;   // wc.z = b_alpha[k]
            h[i] = fmaxf(xiarr[i] + xjarr[i] + a, 0.f);
        }
        // AH0 partial: reduce over jj (8 consecutive lanes)
        #pragma unroll
        for (int i = 0; i < 8; ++i) {
            float v = adjv * h[i];
            v += __shfl_xor(v, 1);
            v += __shfl_xor(v, 2);
            v += __shfl_xor(v, 4);
            if (jj == 0) ah_s[ii][kb + i] += v;
        }
        // split hi/lo, pack, write to LDS
        {
            u32 hi[4], lo[4];
            #pragma unroll
            for (int p = 0; p < 4; ++p) {
                float h0 = h[2*p], h1 = h[2*p+1];
                u32 a0 = rne1(h0), a1 = rne1(h1);
                hi[p] = a0 | (a1 << 16);
                lo[p] = rne1(h0 - bf2f(a0)) | (rne1(h1 - bf2f(a1)) << 16);
            }
            *(uint4*)&hsA[0][wv][m][0] = make_uint4(hi[0], hi[1], hi[2], hi[3]);
            *(uint4*)&hsA[1][wv][m][0] = make_uint4(lo[0], lo[1], lo[2], lo[3]);
        }
        // (c) write W stage to LDS
        #pragma unroll
        for (int hl = 0; hl < 2; ++hl)
            #pragma unroll
            for (int q4 = 0; q4 < 4; ++q4) {
                int f = q4 * 256 + t;
                *(uint4*)&wb[hl][f >> 8][f & 255][0] = wreg[hl][q4];
            }
        __syncthreads();

        // (d) fragments + MFMA: wave wv covers all 4 mt, nt = wv*4 + 0..3
        bf16x8 aH[4], aL[4];
        #pragma unroll
        for (int mt = 0; mt < 4; ++mt) {
            aH[mt] = *(const bf16x8*)&hsA[0][l4][mt * 16 + l16][0];
            aL[mt] = *(const bf16x8*)&hsA[1][l4][mt * 16 + l16][0];
        }
        #pragma unroll
        for (int ntl = 0; ntl < 4; ++ntl) {
            int n = (wv * 4 + ntl) * 16 + l16;
            bf16x8 bH = *(const bf16x8*)&wb[0][l4][n][0];
            bf16x8 bL = *(const bf16x8*)&wb[1][l4][n][0];
            #pragma unroll
            for (int mt = 0; mt < 4; ++mt) {
                acc[mt][ntl] = __builtin_amdgcn_mfma_f32_16x16x32_bf16(aH[mt], bH, acc[mt][ntl], 0, 0, 0);
                acc[mt][ntl] = __builtin_amdgcn_mfma_f32_16x16x32_bf16(aH[mt], bL, acc[mt][ntl], 0, 0, 0);
                acc[mt][ntl] = __builtin_amdgcn_mfma_f32_16x16x32_bf16(aL[mt], bH, acc[mt][ntl], 0, 0, 0);
            }
        }
        __syncthreads();
    }

    // ---- epilogue: relu + bf16-pack alpha1 via LDS staging (2 halves) ----
    #pragma unroll
    for (int h2 = 0; h2 < 2; ++h2) {
        #pragma unroll
        for (int mtl = 0; mtl < 2; ++mtl) {
            int mt = h2 * 2 + mtl;
            #pragma unroll
            for (int ntl = 0; ntl < 4; ++ntl) {
                int n = (wv * 4 + ntl) * 16 + l16;
                #pragma unroll
                for (int r = 0; r < 4; ++r)
                    st[mtl * 16 + l4 * 4 + r][n] = acc[mt][ntl][r];
            }
        }
        __syncthreads();
        #pragma unroll
        for (int p = 0; p < 4; ++p) {
            int f = p * 256 + t;
            int row = f >> 5, u8 = f & 31;           // row 0..31, 8 f32 each
            float4 c0 = *(const float4*)&st[row][u8 * 8];
            float4 c1 = *(const float4*)&st[row][u8 * 8 + 4];
            uint4 pk;
            pk.x = pk2bf(fmaxf(c0.x, 0.f), fmaxf(c0.y, 0.f));
            pk.y = pk2bf(fmaxf(c0.z, 0.f), fmaxf(c0.w, 0.f));
            pk.z = pk2bf(fmaxf(c1.x, 0.f), fmaxf(c1.y, 0.f));
            pk.w = pk2bf(fmaxf(c1.z, 0.f), fmaxf(c1.w, 0.f));
            int mg = h2 * 32 + row;                  // pair row 0..63
            int iw = mg >> 3, jw = mg & 7;
            *(uint4*)&alpha1[((b * 256 + i0 + iw) * 256 + j0 + jw) * 128 + u8 * 4] = pk;
        }
        __syncthreads();
    }

    // ---- AH0 partials out ----
    #pragma unroll
    for (int q = 0; q < 8; ++q)
        ahpart[(((jt * 4 + b) * 32 + it) * 8 + q) * 256 + t] = ah_s[q][t];
}

__global__ __launch_bounds__(256) void reduce_ah(
    const float* __restrict__ part, float* __restrict__ AH0)
{
    int bi = blockIdx.x;
    int b = bi >> 8, i = bi & 255;
    int it = i >> 3, ii = i & 7;
    int t = threadIdx.x;
    float s = 0.f;
    for (int jt = 0; jt < 32; ++jt)
        s += part[(((jt * 4 + b) * 32 + it) * 8 + ii) * 256 + t];
    AH0[bi * 256 + t] = s;
}

// ---------------------------------------------------------------------------
// Pass 2: stream bf16 alpha1, accumulate AH1
// ---------------------------------------------------------------------------
__global__ __launch_bounds__(256) void pass2b(
    const u32* __restrict__ alpha1, const float* __restrict__ xi1,
    const float* __restrict__ xj1b, const float* __restrict__ adj2,
    float* __restrict__ AH1)
{
    __shared__ __align__(16) float partial[4][256];
    int bi = blockIdx.x;
    int b = bi >> 8;
    int t = threadIdx.x;
    int wv = t >> 6, lane = t & 63;
    int k4 = lane * 4;
    float4 xi = *(const float4*)&xi1[bi * 256 + k4];
    float4 acc = {0.f, 0.f, 0.f, 0.f};
    size_t base = (size_t)bi * 32768;   // u32 units: 256*128
    const float* a2row = &adj2[bi * 256];
    for (int j = wv; j < 256; j += 4) {
        float a2 = a2row[j];
        float4 xj = *(const float4*)&xj1b[(b * 256 + j) * 256 + k4];
        uint2 q = *(const uint2*)&alpha1[base + j * 128 + (k4 >> 1)];
        float4 al;
        al.x = bf2f(q.x & 0xFFFFu); al.y = bf2f(q.x >> 16);
        al.z = bf2f(q.y & 0xFFFFu); al.w = bf2f(q.y >> 16);
        acc.x += a2 * fmaxf(xi.x + xj.x + al.x, 0.f);
        acc.y += a2 * fmaxf(xi.y + xj.y + al.y, 0.f);
        acc.z += a2 * fmaxf(xi.z + xj.z + al.z, 0.f);
        acc.w += a2 * fmaxf(xi.w + xj.w + al.w, 0.f);
    }
    *(float4*)&partial[wv][k4] = acc;
    __syncthreads();
    if (wv == 0) {
        float4 p0 = *(const float4*)&partial[0][k4];
        float4 p1 = *(const float4*)&partial[1][k4];
        float4 p2 = *(const float4*)&partial[2][k4];
        float4 p3 = *(const float4*)&partial[3][k4];
        float4 o;
        o.x = p0.x + p1.x + p2.x + p3.x;
        o.y = p0.y + p1.y + p2.y + p3.y;
        o.z = p0.z + p1.z + p2.z + p3.z;
        o.w = p0.w + p1.w + p2.w + p3.w;
        *(float4*)&AH1[bi * 256 + k4] = o;
    }
}

// ---------------------------------------------------------------------------
// Tier C fallback kernels (tiny-ws path) — unchanged from round 3
// ---------------------------------------------------------------------------
__global__ __launch_bounds__(256) void pass1C(
    const float* __restrict__ rel, const float* __restrict__ Wat,
    const float* __restrict__ b_alpha, const float* __restrict__ xi0,
    const float* __restrict__ xj0b, const float* __restrict__ adj2,
    float* __restrict__ AH0)
{
    __shared__ float xj_s[16][257];
    __shared__ float rel_s[16 * 48];
    __shared__ float adj_sC[128];
    int t = threadIdx.x;
    int it = blockIdx.x, b = blockIdx.y;
    int i0 = it * 8;
    float xiv[8], watv[6];
    #pragma unroll
    for (int ii = 0; ii < 8; ++ii) xiv[ii] = xi0[(b * 256 + i0 + ii) * 256 + t];
    #pragma unroll
    for (int c = 0; c < 6; ++c) watv[c] = Wat[c * 256 + t];
    float bav = b_alpha[t];
    float ah[8] = {};
    for (int jc = 0; jc < 256; jc += 16) {
        __syncthreads();
        #pragma unroll
        for (int q = 0; q < 16; ++q) xj_s[q][t] = xj0b[(b * 256 + jc + q) * 256 + t];
        for (int e = t; e < 768; e += 256) {
            int jjp = e / 48, r = e % 48;
            rel_s[e] = rel[((b * 256 + i0 + r / 6) * 256 + jc + jjp) * 6 + (r % 6)];
        }
        if (t < 128) adj_sC[t] = adj2[(b * 256 + i0 + (t & 7)) * 256 + jc + (t >> 3)];
        __syncthreads();
        for (int jjp = 0; jjp < 16; ++jjp) {
            float xjv = xj_s[jjp][t];
            #pragma unroll
            for (int ii = 0; ii < 8; ++ii) {
                float a = bav;
                #pragma unroll
                for (int c = 0; c < 6; ++c) a += rel_s[jjp * 48 + ii * 6 + c] * watv[c];
                float h = fmaxf(xiv[ii] + xjv + a, 0.f);
                ah[ii] += adj_sC[jjp * 8 + ii] * h;
            }
        }
    }
    #pragma unroll
    for (int ii = 0; ii < 8; ++ii)
        AH0[(b * 256 + i0 + ii) * 256 + t] = ah[ii];
}

__global__ __launch_bounds__(256) void pass2C(
    const float* __restrict__ rel, const float* __restrict__ Wat,
    const float* __restrict__ b_alpha, const float* __restrict__ xi0,
    const float* __restrict__ xj0b, const float* __restrict__ w_alpha0,
    const float* __restrict__ xi1, const float* __restrict__ xj1b,
    const float* __restrict__ adj2, float* __restrict__ AH1)
{
    __shared__ float xi_s[8][257];
    __shared__ float xj_s[8][257];
    __shared__ float xj1_s[8][257];
    __shared__ __align__(16) float wat_s[6][256];
    __shared__ __align__(16) float ba_s[256];
    __shared__ __align__(16) float rel_s[6][64];
    __shared__ __align__(16) float adj_s[64];
    __shared__ __align__(16) float hs[16][64];
    __shared__ __align__(16) float ws_s[16][256];

    int t = threadIdx.x;
    int it = blockIdx.x, b = blockIdx.y;
    int i0 = it * 8;
    int rg = t >> 5, cg = t & 31;
    int lane = t & 63, wv = t >> 6;
    int ii_l = lane >> 3, jj_l = lane & 7;

    #pragma unroll
    for (int q = 0; q < 8; ++q) xi_s[q][t] = xi0[(b * 256 + i0 + q) * 256 + t];
    #pragma unroll
    for (int q = 0; q < 6; ++q) wat_s[q][t] = Wat[q * 256 + t];
    ba_s[t] = b_alpha[t];
    float xi1v[8];
    #pragma unroll
    for (int y = 0; y < 8; ++y) xi1v[y] = xi1[(b * 256 + i0 + rg) * 256 + cg * 8 + y];
    float ah1[8] = {};

    for (int jt = 0; jt < 32; ++jt) {
        int j0 = jt * 8;
        __syncthreads();
        #pragma unroll
        for (int q = 0; q < 8; ++q) {
            xj_s[q][t]  = xj0b[(b * 256 + j0 + q) * 256 + t];
            xj1_s[q][t] = xj1b[(b * 256 + j0 + q) * 256 + t];
        }
        for (int e = t; e < 384; e += 256) {
            int ii = e / 48, rem = e % 48;
            int jjp = rem / 6, c = rem % 6;
            rel_s[c][ii * 8 + jjp] = rel[((b * 256 + i0 + ii) * 256 + j0 + jjp) * 6 + c];
        }
        if (t < 64) adj_s[t] = adj2[(b * 256 + i0 + (t >> 3)) * 256 + j0 + (t & 7)];

        float acc[8][8] = {};
        for (int c = 0; c < 16; ++c) {
            __syncthreads();
            #pragma unroll
            for (int p = 0; p < 4; ++p) {
                int klocal = wv + p * 4;
                int kg = c * 16 + klocal;
                float a = ba_s[kg];
                #pragma unroll
                for (int cc = 0; cc < 6; ++cc) a += rel_s[cc][lane] * wat_s[cc][kg];
                float h = xi_s[ii_l][kg] + xj_s[jj_l][kg] + a;
                hs[klocal][lane] = fmaxf(h, 0.f);
            }
            #pragma unroll
            for (int q = 0; q < 4; ++q) {
                int f = q * 256 + t;
                int row = f >> 6, col4 = f & 63;
                *(float4*)&ws_s[row][col4 * 4] =
                    *(const float4*)&w_alpha0[(c * 16 + row) * 256 + col4 * 4];
            }
            __syncthreads();
            #pragma unroll
            for (int kk = 0; kk < 16; ++kk) {
                float4 a0 = *(const float4*)&hs[kk][rg * 8];
                float4 a1 = *(const float4*)&hs[kk][rg * 8 + 4];
                float4 b0 = *(const float4*)&ws_s[kk][cg * 8];
                float4 b1 = *(const float4*)&ws_s[kk][cg * 8 + 4];
                float av[8] = {a0.x, a0.y, a0.z, a0.w, a1.x, a1.y, a1.z, a1.w};
                float bv[8] = {b0.x, b0.y, b0.z, b0.w, b1.x, b1.y, b1.z, b1.w};
                #pragma unroll
                for (int x = 0; x < 8; ++x)
                    #pragma unroll
                    for (int y = 0; y < 8; ++y)
                        acc[x][y] += av[x] * bv[y];
            }
        }
        #pragma unroll
        for (int x = 0; x < 8; ++x) {
            float a2 = adj_s[rg * 8 + x];
            #pragma unroll
            for (int y = 0; y < 8; ++y) {
                float al = fmaxf(acc[x][y], 0.f);
                float h1 = fmaxf(xi1v[y] + xj1_s[x][cg * 8 + y] + al, 0.f);
                ah1[y] += a2 * h1;
            }
        }
    }
    #pragma unroll
    for (int y = 0; y < 8; ++y)
        AH1[(b * 256 + i0 + rg) * 256 + cg * 8 + y] = ah1[y];
}

// ---------------------------------------------------------------------------
extern "C" void kernel_launch(void* const* d_in, const int* in_sizes, int n_in,
                              void* d_out, int out_size, void* d_ws, size_t ws_size,
                              hipStream_t stream)
{
    const float* x        = (const float*)d_in[0];
    const float* rel      = (const float*)d_in[1];
    const float* adj      = (const float*)d_in[2];
    const int*   box_num  = (const int*)d_in[3];
    const float* Wat      = (const float*)d_in[4];
    const float* b_alpha  = (const float*)d_in[5];
    const float* W_proj   = (const float*)d_in[6];
    const float* b_proj   = (const float*)d_in[7];
    const float* learn_w  = (const float*)d_in[8];
    const float* w_alpha0 = (const float*)d_in[9];
    const float* w_vi0    = (const float*)d_in[10];
    const float* w_vj0    = (const float*)d_in[11];
    const float* bias_h0  = (const float*)d_in[12];
    const float* w_node0  = (const float*)d_in[13];
    // d_in[14] = l1_w_alpha (unused: layer-1 new_alpha is discarded)
    const float* w_vi1    = (const float*)d_in[15];
    const float* w_vj1    = (const float*)d_in[16];
    const float* bias_h1  = (const float*)d_in[17];
    const float* w_node1  = (const float*)d_in[18];

    // ---- workspace layout ----
    float* sm    = (float*)d_ws;
    float* adj2  = sm;                 // 262,144
    float* xhat  = adj2  + 262144;     // 131,072
    float* xi0   = xhat  + 131072;     // 262,144
    float* xj0b  = xi0   + 262144;     // 262,144
    float* AH0   = xj0b  + 262144;     // 262,144
    float* x1    = AH0   + 262144;     // 262,144
    float* xi1   = x1    + 262144;     // 262,144
    float* xj1b  = xi1   + 262144;     // 262,144
    float* AH1   = xj1b  + 262144;     // 262,144
    float* rowP1 = AH1   + 262144;     //   1,024
    float* rowP2 = rowP1 + 1024;       //   1,024
    const size_t SMALLS_F = 2230272;   // floats
    const size_t WTP_F    = 65536;     // 256 KB packed hi/lo W
    const size_t PART_F   = 8388608;
    u32*   wTp    = (u32*)(sm + SMALLS_F);
    float* part   = sm + SMALLS_F + WTP_F;
    u32*   alpha1 = (u32*)(sm + SMALLS_F + WTP_F + PART_F);   // bf16-packed, 128 MiB

    const size_t needM = (SMALLS_F + WTP_F + PART_F) * 4ULL + 134217728ULL;  // ~169 MB
    int use_mfma = (ws_size >= needM);

    float* out_x2   = (float*)d_out;
    float* out_soft = out_x2 + 262144;
    float* out_gl   = out_soft + 262144;

    // Phase A: graph learning
    gemm64<<<dim3(16, 2), 256, 0, stream>>>(x, W_proj, b_proj, nullptr, xhat, 1024, 256, 128, 0);
    soft_adj_kernel<<<1024, 256, 0, stream>>>(xhat, adj, box_num, learn_w, out_soft, adj2, rowP1, rowP2);
    gl_loss_kernel<<<4, 256, 0, stream>>>(rowP1, rowP2, box_num, out_gl);

    // Layer 0 projections (bias_h0 folded into xj)
    gemm64<<<dim3(16, 4), 256, 0, stream>>>(x, w_vi0, nullptr, nullptr, xi0, 1024, 256, 256, 0);
    gemm64<<<dim3(16, 4), 256, 0, stream>>>(x, w_vj0, nullptr, bias_h0, xj0b, 1024, 256, 256, 0);

    // Layer 0 heavy pass
    if (use_mfma) {
        wprep<<<32, 256, 0, stream>>>(w_alpha0, wTp);
        pass1M<<<dim3(32, 32, 4), 256, 0, stream>>>(rel, Wat, b_alpha, xi0, xj0b, adj2, wTp, alpha1, part);
        reduce_ah<<<1024, 256, 0, stream>>>(part, AH0);
    } else {
        pass1C<<<dim3(32, 4), 256, 0, stream>>>(rel, Wat, b_alpha, xi0, xj0b, adj2, AH0);
    }

    // Layer 0 node update + layer 1 projections
    gemm64<<<dim3(16, 4), 256, 0, stream>>>(AH0, w_node0, nullptr, nullptr, x1, 1024, 256, 256, 1);
    gemm64<<<dim3(16, 4), 256, 0, stream>>>(x1, w_vi1, nullptr, nullptr, xi1, 1024, 256, 256, 0);
    gemm64<<<dim3(16, 4), 256, 0, stream>>>(x1, w_vj1, nullptr, bias_h1, xj1b, 1024, 256, 256, 0);

    // Layer 1 -> AH1
    if (use_mfma) {
        pass2b<<<1024, 256, 0, stream>>>(alpha1, xi1, xj1b, adj2, AH1);
    } else {
        pass2C<<<dim3(32, 4), 256, 0, stream>>>(rel, Wat, b_alpha, xi0, xj0b, w_alpha0, xi1, xj1b, adj2, AH1);
    }

    // Final node update -> x2
    gemm64<<<dim3(16, 4), 256, 0, stream>>>(AH1, w_node1, nullptr, nullptr, out_x2, 1024, 256, 256, 1);
}

// Round 5
// 406.577 us; speedup vs baseline: 1.8989x; 1.1780x over previous
//
#include <hip/hip_runtime.h>

// Problem constants
#define NB 4
#define NN 256
#define ND 256
#define NL 128
#define NK 256
static constexpr float GAMMA_C = 1e-4f;
static constexpr float ETA_C = 1.0f;

typedef unsigned int u32;
typedef __attribute__((ext_vector_type(8))) short bf16x8;
typedef __attribute__((ext_vector_type(4))) float f32x4;

__device__ __forceinline__ u32 rne1(float x) {            // f32 -> bf16 bits (RNE)
    u32 a = __float_as_uint(x);
    return (a + 0x7FFFu + ((a >> 16) & 1u)) >> 16;
}
__device__ __forceinline__ float bf2f(u32 v) { return __uint_as_float(v << 16); }
__device__ __forceinline__ u32 pk2bf(float lo, float hi) { return rne1(lo) | (rne1(hi) << 16); }

struct GJob {
    const float* A; const float* W; const float* bias; const float* addm;
    float* C; int Kd; int Nc; int relu;
};

// ---------------------------------------------------------------------------
// Generic small GEMM: C[M,Nc] = act(A[M,K] @ W[K,Nc] + bias[col] + addm[row%256,col])
// ---------------------------------------------------------------------------
__device__ __forceinline__ void gemm64_body(
    const float* __restrict__ A, const float* __restrict__ W,
    const float* __restrict__ bias, const float* __restrict__ addm,
    float* __restrict__ C, int Kd, int Nc, int relu_act)
{
    __shared__ __align__(16) float As[16][68];
    __shared__ __align__(16) float Ws[16][64];
    int t = threadIdx.x;
    int r0 = blockIdx.x * 64, c0 = blockIdx.y * 64;
    int ty = t >> 4, tx = t & 15;
    float acc[4][4] = {};
    for (int kc = 0; kc < Kd; kc += 16) {
        __syncthreads();
        #pragma unroll
        for (int q = 0; q < 4; ++q) {
            int f = q * 256 + t;
            int row = f >> 4, kk = f & 15;
            As[kk][row] = A[(r0 + row) * Kd + kc + kk];
        }
        #pragma unroll
        for (int q = 0; q < 4; ++q) {
            int f = q * 256 + t;
            int kk = f >> 6, col = f & 63;
            Ws[kk][col] = W[(kc + kk) * Nc + c0 + col];
        }
        __syncthreads();
        #pragma unroll
        for (int kk = 0; kk < 16; ++kk) {
            float4 av = *(const float4*)&As[kk][ty * 4];
            float4 bv = *(const float4*)&Ws[kk][tx * 4];
            float a[4] = {av.x, av.y, av.z, av.w};
            float b[4] = {bv.x, bv.y, bv.z, bv.w};
            #pragma unroll
            for (int i = 0; i < 4; ++i)
                #pragma unroll
                for (int j = 0; j < 4; ++j)
                    acc[i][j] += a[i] * b[j];
        }
    }
    #pragma unroll
    for (int i = 0; i < 4; ++i) {
        int row = r0 + ty * 4 + i;
        #pragma unroll
        for (int j = 0; j < 4; ++j) {
            int col = c0 + tx * 4 + j;
            float v = acc[i][j];
            if (bias) v += bias[col];
            if (addm) v += addm[(row & 255) * Nc + col];
            if (relu_act) v = fmaxf(v, 0.f);
            C[row * Nc + col] = v;
        }
    }
}

__global__ __launch_bounds__(256) void gemm64(
    const float* __restrict__ A, const float* __restrict__ W,
    const float* __restrict__ bias, const float* __restrict__ addm,
    float* __restrict__ C, int M, int Kd, int Nc, int relu_act)
{
    gemm64_body(A, W, bias, addm, C, Kd, Nc, relu_act);
}

// Fused multi-GEMM: blockIdx.z selects the job (jobs may have Nc=128 -> skip tail y)
__global__ __launch_bounds__(256) void gemm64_multi(GJob j0, GJob j1, GJob j2)
{
    GJob jb = (blockIdx.z == 0) ? j0 : (blockIdx.z == 1) ? j1 : j2;
    if ((int)blockIdx.y * 64 >= jb.Nc) return;     // uniform per block
    gemm64_body(jb.A, jb.W, jb.bias, jb.addm, jb.C, jb.Kd, jb.Nc, jb.relu);
}

// ---------------------------------------------------------------------------
// Graph learning: per (b,i) row -> soft_adj, adj2, loss partials
// ---------------------------------------------------------------------------
__global__ __launch_bounds__(256) void soft_adj_kernel(
    const float* __restrict__ xhat, const float* __restrict__ adj,
    const int* __restrict__ box_num, const float* __restrict__ learn_w,
    float* __restrict__ soft_out, float* __restrict__ adj2,
    float* __restrict__ rowP1, float* __restrict__ rowP2)
{
    __shared__ __align__(16) float xs[NL];
    __shared__ __align__(16) float lw[NL];
    __shared__ float red[256];
    int bi = blockIdx.x;            // b*256 + i
    int b = bi >> 8, i = bi & 255;
    int j = threadIdx.x;
    if (j < NL) { xs[j] = xhat[bi * NL + j]; lw[j] = learn_w[j]; }
    __syncthreads();
    float sumw = 0.f;
    for (int d = 0; d < NL; ++d) sumw += lw[d];
    float s1 = 0.f, s2 = 0.f;
    const float* xj = &xhat[(b * 256 + j) * NL];
    #pragma unroll 4
    for (int d = 0; d < NL; d += 4) {
        float4 a = *(const float4*)&xs[d];
        float4 bb = *(const float4*)&xj[d];
        float d0 = a.x - bb.x, d1 = a.y - bb.y, d2 = a.z - bb.z, d3 = a.w - bb.w;
        s1 += fabsf(d0) * lw[d] + fabsf(d1) * lw[d + 1] + fabsf(d2) * lw[d + 2] + fabsf(d3) * lw[d + 3];
        s2 += d0 * d0 + d1 * d1 + d2 * d2 + d3 * d3;
    }
    int bn = box_num[b];
    float maskv = (i < bn && j < bn) ? 0.f : -1.f;
    float out = s1 + maskv * sumw;
    out = (out >= 0.f) ? out : 0.01f * out;     // leaky_relu slope 0.01
    float pn = sqrtf(s2 + 1e-12f);
    red[j] = out; __syncthreads();
    for (int s = 128; s > 0; s >>= 1) { if (j < s) red[j] = fmaxf(red[j], red[j + s]); __syncthreads(); }
    float m = red[0]; __syncthreads();
    float aij = adj[bi * 256 + j];
    float e = expf(out - m) * aij;
    red[j] = e; __syncthreads();
    for (int s = 128; s > 0; s >>= 1) { if (j < s) red[j] += red[j + s]; __syncthreads(); }
    float S = red[0]; __syncthreads();
    float soft = e / S + 1e-10f;
    soft_out[bi * 256 + j] = soft;
    adj2[bi * 256 + j] = aij * soft;
    float p1 = expf(soft + ETA_C * pn);
    float p2 = soft * soft;
    red[j] = p1; __syncthreads();
    for (int s = 128; s > 0; s >>= 1) { if (j < s) red[j] += red[j + s]; __syncthreads(); }
    if (j == 0) rowP1[bi] = red[0];
    __syncthreads();
    red[j] = p2; __syncthreads();
    for (int s = 128; s > 0; s >>= 1) { if (j < s) red[j] += red[j + s]; __syncthreads(); }
    if (j == 0) rowP2[bi] = red[0];
}

__global__ __launch_bounds__(256) void gl_loss_kernel(
    const float* __restrict__ rowP1, const float* __restrict__ rowP2,
    const int* __restrict__ box_num, float* __restrict__ out)
{
    __shared__ float r1[256], r2[256];
    int b = blockIdx.x, t = threadIdx.x;
    r1[t] = rowP1[b * 256 + t];
    r2[t] = rowP2[b * 256 + t];
    __syncthreads();
    for (int s = 128; s > 0; s >>= 1) { if (t < s) { r1[t] += r1[t + s]; r2[t] += r2[t + s]; } __syncthreads(); }
    if (t == 0) {
        float bn = (float)box_num[b];
        out[b] = r1[0] / (bn * bn) + GAMMA_C * sqrtf(r2[0]);
    }
}

// ---------------------------------------------------------------------------
// W prep: split w_alpha0 (256x256, k-major) into hi/lo bf16, packed u32 pairs:
//   wTp[hl][c(8)][kgl(4)][n(256)][q(4)], u32 q packs k = c*32+kgl*8+2q, +1
// ---------------------------------------------------------------------------
__global__ __launch_bounds__(256) void wprep(
    const float* __restrict__ w_alpha0, u32* __restrict__ wTp)
{
    int c = blockIdx.x >> 2, kgl = blockIdx.x & 3;
    int n = threadIdx.x;
    #pragma unroll
    for (int q = 0; q < 4; ++q) {
        int k = c * 32 + kgl * 8 + 2 * q;
        float w0 = w_alpha0[k * 256 + n];
        float w1 = w_alpha0[(k + 1) * 256 + n];
        u32 h0 = rne1(w0), h1 = rne1(w1);
        float l0 = w0 - bf2f(h0), l1 = w1 - bf2f(h1);
        wTp[(((0 * 8 + c) * 4 + kgl) * 256 + n) * 4 + q] = h0 | (h1 << 16);
        wTp[(((1 * 8 + c) * 4 + kgl) * 256 + n) * 4 + q] = rne1(l0) | (rne1(l1) << 16);
    }
}

// ---------------------------------------------------------------------------
// Pass 1 (MFMA): per (b, 8i, 8j) tile: H0 on-the-fly (f32) -> split hi/lo bf16
// -> alpha1 = relu(H0 @ w_alpha0) via bf16x3 MFMA (error ~2^-16), stored packed
// bf16. AH0 partials via in-register butterfly + direct coalesced global store.
// LDS 48KB -> 3 blocks/CU (was 58.9KB / 2 blocks).
// ---------------------------------------------------------------------------
__global__ __launch_bounds__(256) void pass1M(
    const float* __restrict__ rel, const float* __restrict__ Wat,
    const float* __restrict__ b_alpha, const float* __restrict__ xi0,
    const float* __restrict__ xj0b, const float* __restrict__ adj2,
    const u32* __restrict__ wTp,
    u32* __restrict__ alpha1, float* __restrict__ ahpart)
{
    __shared__ __align__(16) float watb_s[256][8];   // {Wat[0..5][k], b_alpha[k], 0}
    __shared__ __align__(16) u32 hsA[2][4][64][4];   // [hl][kgl][m][4u32]
    __shared__ __align__(16) char wbraw[32768];      // wb[2][4][256][4] u32 / st[16][260] f32
    u32 (*wb)[4][256][4] = (u32(*)[4][256][4])wbraw;
    float (*st)[260] = (float(*)[260])wbraw;

    int t = threadIdx.x;
    int jt = blockIdx.x, it = blockIdx.y, b = blockIdx.z;
    int i0 = it * 8, j0 = jt * 8;
    int m = t & 63, wv = t >> 6;       // lane == m; wave id wv
    int ii = m >> 3, jj = m & 7;
    int l4 = m >> 4, l16 = m & 15;

    // block-start staging
    #pragma unroll
    for (int q = 0; q < 8; ++q)
        watb_s[t][q] = (q < 6) ? Wat[q * 256 + t] : (q == 6 ? b_alpha[t] : 0.f);
    float relv2[6];
    #pragma unroll
    for (int c = 0; c < 6; ++c)
        relv2[c] = rel[((b * 256 + i0 + ii) * 256 + j0 + jj) * 6 + c];
    float adjv = adj2[(b * 256 + i0 + ii) * 256 + j0 + jj];
    float* ahbase = &ahpart[(((jt * 4 + b) * 32 + it) * 8 + ii) * 256];

    f32x4 acc[4][4];
    #pragma unroll
    for (int a = 0; a < 4; ++a)
        #pragma unroll
        for (int c = 0; c < 4; ++c)
            acc[a][c] = (f32x4){0.f, 0.f, 0.f, 0.f};

    __syncthreads();

    for (int c = 0; c < 8; ++c) {
        // (a) issue W-stage global loads early (latency hides under H-compute)
        uint4 wreg[2][4];
        #pragma unroll
        for (int hl = 0; hl < 2; ++hl)
            #pragma unroll
            for (int q4 = 0; q4 < 4; ++q4) {
                int f = q4 * 256 + t;
                wreg[hl][q4] = *(const uint4*)&wTp[(hl * 8 + c) * 4096 + f * 4];
            }

        // (b) H0 chunk: thread computes h(m, k) for k = c*32 + wv*8 + 0..7
        int kb = c * 32 + wv * 8;
        float xiarr[8], xjarr[8];
        {
            const float4* xa = (const float4*)&xi0[(b * 256 + i0 + ii) * 256 + kb];
            float4 x0 = xa[0], x1 = xa[1];
            xiarr[0]=x0.x; xiarr[1]=x0.y; xiarr[2]=x0.z; xiarr[3]=x0.w;
            xiarr[4]=x1.x; xiarr[5]=x1.y; xiarr[6]=x1.z; xiarr[7]=x1.w;
            const float4* xb = (const float4*)&xj0b[(b * 256 + j0 + jj) * 256 + kb];
            float4 y0 = xb[0], y1 = xb[1];
            xjarr[0]=y0.x; xjarr[1]=y0.y; xjarr[2]=y0.z; xjarr[3]=y0.w;
            xjarr[4]=y1.x; xjarr[5]=y1.y; xjarr[6]=y1.z; xjarr[7]=y1.w;
        }
        float h[8];
        #pragma unroll
        for (int i = 0; i < 8; ++i) {
            int k = kb + i;
            float4 wa = *(const float4*)&watb_s[k][0];   // uniform-address broadcast
            float4 wc = *(const float4*)&watb_s[k][4];
            float a = relv2[0]*wa.x + relv2[1]*wa.y + relv2[2]*wa.z + relv2[3]*wa.w
                    + relv2[4]*wc.x + relv2[5]*wc.y + wc.z;   // wc.z = b_alpha[k]
            h[i] = fmaxf(xiarr[i] + xjarr[i] + a, 0.f);
        }
        // AH0 partial: butterfly over jj (all 8 lanes get the sum), lane jj
        // keeps i==jj, then one coalesced 4B store per lane (8x32B runs/wave).
        {
            float ahv = 0.f;
            #pragma unroll
            for (int i = 0; i < 8; ++i) {
                float v = adjv * h[i];
                v += __shfl_xor(v, 1);
                v += __shfl_xor(v, 2);
                v += __shfl_xor(v, 4);
                ahv = (jj == i) ? v : ahv;
            }
            ahbase[kb + jj] = ahv;
        }
        // split hi/lo, pack, write to LDS
        {
            u32 hi[4], lo[4];
            #pragma unroll
            for (int p = 0; p < 4; ++p) {
                float h0 = h[2*p], h1 = h[2*p+1];
                u32 a0 = rne1(h0), a1 = rne1(h1);
                hi[p] = a0 | (a1 << 16);
                lo[p] = rne1(h0 - bf2f(a0)) | (rne1(h1 - bf2f(a1)) << 16);
            }
            *(uint4*)&hsA[0][wv][m][0] = make_uint4(hi[0], hi[1], hi[2], hi[3]);
            *(uint4*)&hsA[1][wv][m][0] = make_uint4(lo[0], lo[1], lo[2], lo[3]);
        }
        // (c) write W stage to LDS
        #pragma unroll
        for (int hl = 0; hl < 2; ++hl)
            #pragma unroll
            for (int q4 = 0; q4 < 4; ++q4) {
                int f = q4 * 256 + t;
                *(uint4*)&wb[hl][f >> 8][f & 255][0] = wreg[hl][q4];
            }
        __syncthreads();

        // (d) fragments + MFMA: wave wv covers all 4 mt, nt = wv*4 + 0..3
        bf16x8 aH[4], aL[4];
        #pragma unroll
        for (int mt = 0; mt < 4; ++mt) {
            aH[mt] = *(const bf16x8*)&hsA[0][l4][mt * 16 + l16][0];
            aL[mt] = *(const bf16x8*)&hsA[1][l4][mt * 16 + l16][0];
        }
        #pragma unroll
        for (int ntl = 0; ntl < 4; ++ntl) {
            int n = (wv * 4 + ntl) * 16 + l16;
            bf16x8 bH = *(const bf16x8*)&wb[0][l4][n][0];
            bf16x8 bL = *(const bf16x8*)&wb[1][l4][n][0];
            #pragma unroll
            for (int mt = 0; mt < 4; ++mt) {
                acc[mt][ntl] = __builtin_amdgcn_mfma_f32_16x16x32_bf16(aH[mt], bH, acc[mt][ntl], 0, 0, 0);
                acc[mt][ntl] = __builtin_amdgcn_mfma_f32_16x16x32_bf16(aH[mt], bL, acc[mt][ntl], 0, 0, 0);
                acc[mt][ntl] = __builtin_amdgcn_mfma_f32_16x16x32_bf16(aL[mt], bH, acc[mt][ntl], 0, 0, 0);
            }
        }
        __syncthreads();
    }

    // ---- epilogue: relu + bf16-pack alpha1 via LDS staging, 4 quarter-passes ----
    #pragma unroll
    for (int mt = 0; mt < 4; ++mt) {
        #pragma unroll
        for (int ntl = 0; ntl < 4; ++ntl) {
            int n = (wv * 4 + ntl) * 16 + l16;
            #pragma unroll
            for (int r = 0; r < 4; ++r)
                st[l4 * 4 + r][n] = acc[mt][ntl][r];
        }
        __syncthreads();
        #pragma unroll
        for (int p = 0; p < 2; ++p) {
            int f = p * 256 + t;                     // 0..511
            int row = f >> 5, u8 = f & 31;           // row 0..15, 8 f32 each
            float4 c0 = *(const float4*)&st[row][u8 * 8];
            float4 c1 = *(const float4*)&st[row][u8 * 8 + 4];
            uint4 pk;
            pk.x = pk2bf(fmaxf(c0.x, 0.f), fmaxf(c0.y, 0.f));
            pk.y = pk2bf(fmaxf(c0.z, 0.f), fmaxf(c0.w, 0.f));
            pk.z = pk2bf(fmaxf(c1.x, 0.f), fmaxf(c1.y, 0.f));
            pk.w = pk2bf(fmaxf(c1.z, 0.f), fmaxf(c1.w, 0.f));
            int mg = mt * 16 + row;                  // pair row 0..63
            int iw = mg >> 3, jw = mg & 7;
            *(uint4*)&alpha1[((b * 256 + i0 + iw) * 256 + j0 + jw) * 128 + u8 * 4] = pk;
        }
        __syncthreads();
    }
}

__global__ __launch_bounds__(256) void reduce_ah(
    const float* __restrict__ part, float* __restrict__ AH0)
{
    int bi = blockIdx.x;
    int b = bi >> 8, i = bi & 255;
    int it = i >> 3, ii = i & 7;
    int t = threadIdx.x;
    float s = 0.f;
    for (int jt = 0; jt < 32; ++jt)
        s += part[(((jt * 4 + b) * 32 + it) * 8 + ii) * 256 + t];
    AH0[bi * 256 + t] = s;
}

// ---------------------------------------------------------------------------
// Pass 2: stream bf16 alpha1, accumulate AH1
// ---------------------------------------------------------------------------
__global__ __launch_bounds__(256) void pass2b(
    const u32* __restrict__ alpha1, const float* __restrict__ xi1,
    const float* __restrict__ xj1b, const float* __restrict__ adj2,
    float* __restrict__ AH1)
{
    __shared__ __align__(16) float partial[4][256];
    int bi = blockIdx.x;
    int b = bi >> 8;
    int t = threadIdx.x;
    int wv = t >> 6, lane = t & 63;
    int k4 = lane * 4;
    float4 xi = *(const float4*)&xi1[bi * 256 + k4];
    float4 acc = {0.f, 0.f, 0.f, 0.f};
    size_t base = (size_t)bi * 32768;   // u32 units: 256*128
    const float* a2row = &adj2[bi * 256];
    for (int j = wv; j < 256; j += 4) {
        float a2 = a2row[j];
        float4 xj = *(const float4*)&xj1b[(b * 256 + j) * 256 + k4];
        uint2 q = *(const uint2*)&alpha1[base + j * 128 + (k4 >> 1)];
        float4 al;
        al.x = bf2f(q.x & 0xFFFFu); al.y = bf2f(q.x >> 16);
        al.z = bf2f(q.y & 0xFFFFu); al.w = bf2f(q.y >> 16);
        acc.x += a2 * fmaxf(xi.x + xj.x + al.x, 0.f);
        acc.y += a2 * fmaxf(xi.y + xj.y + al.y, 0.f);
        acc.z += a2 * fmaxf(xi.z + xj.z + al.z, 0.f);
        acc.w += a2 * fmaxf(xi.w + xj.w + al.w, 0.f);
    }
    *(float4*)&partial[wv][k4] = acc;
    __syncthreads();
    if (wv == 0) {
        float4 p0 = *(const float4*)&partial[0][k4];
        float4 p1 = *(const float4*)&partial[1][k4];
        float4 p2 = *(const float4*)&partial[2][k4];
        float4 p3 = *(const float4*)&partial[3][k4];
        float4 o;
        o.x = p0.x + p1.x + p2.x + p3.x;
        o.y = p0.y + p1.y + p2.y + p3.y;
        o.z = p0.z + p1.z + p2.z + p3.z;
        o.w = p0.w + p1.w + p2.w + p3.w;
        *(float4*)&AH1[bi * 256 + k4] = o;
    }
}

// ---------------------------------------------------------------------------
// Tier C fallback kernels (tiny-ws path)
// ---------------------------------------------------------------------------
__global__ __launch_bounds__(256) void pass1C(
    const float* __restrict__ rel, const float* __restrict__ Wat,
    const float* __restrict__ b_alpha, const float* __restrict__ xi0,
    const float* __restrict__ xj0b, const float* __restrict__ adj2,
    float* __restrict__ AH0)
{
    __shared__ float xj_s[16][257];
    __shared__ float rel_s[16 * 48];
    __shared__ float adj_sC[128];
    int t = threadIdx.x;
    int it = blockIdx.x, b = blockIdx.y;
    int i0 = it * 8;
    float xiv[8], watv[6];
    #pragma unroll
    for (int ii = 0; ii < 8; ++ii) xiv[ii] = xi0[(b * 256 + i0 + ii) * 256 + t];
    #pragma unroll
    for (int c = 0; c < 6; ++c) watv[c] = Wat[c * 256 + t];
    float bav = b_alpha[t];
    float ah[8] = {};
    for (int jc = 0; jc < 256; jc += 16) {
        __syncthreads();
        #pragma unroll
        for (int q = 0; q < 16; ++q) xj_s[q][t] = xj0b[(b * 256 + jc + q) * 256 + t];
        for (int e = t; e < 768; e += 256) {
            int jjp = e / 48, r = e % 48;
            rel_s[e] = rel[((b * 256 + i0 + r / 6) * 256 + jc + jjp) * 6 + (r % 6)];
        }
        if (t < 128) adj_sC[t] = adj2[(b * 256 + i0 + (t & 7)) * 256 + jc + (t >> 3)];
        __syncthreads();
        for (int jjp = 0; jjp < 16; ++jjp) {
            float xjv = xj_s[jjp][t];
            #pragma unroll
            for (int ii = 0; ii < 8; ++ii) {
                float a = bav;
                #pragma unroll
                for (int c = 0; c < 6; ++c) a += rel_s[jjp * 48 + ii * 6 + c] * watv[c];
                float h = fmaxf(xiv[ii] + xjv + a, 0.f);
                ah[ii] += adj_sC[jjp * 8 + ii] * h;
            }
        }
    }
    #pragma unroll
    for (int ii = 0; ii < 8; ++ii)
        AH0[(b * 256 + i0 + ii) * 256 + t] = ah[ii];
}

__global__ __launch_bounds__(256) void pass2C(
    const float* __restrict__ rel, const float* __restrict__ Wat,
    const float* __restrict__ b_alpha, const float* __restrict__ xi0,
    const float* __restrict__ xj0b, const float* __restrict__ w_alpha0,
    const float* __restrict__ xi1, const float* __restrict__ xj1b,
    const float* __restrict__ adj2, float* __restrict__ AH1)
{
    __shared__ float xi_s[8][257];
    __shared__ float xj_s[8][257];
    __shared__ float xj1_s[8][257];
    __shared__ __align__(16) float wat_s[6][256];
    __shared__ __align__(16) float ba_s[256];
    __shared__ __align__(16) float rel_s[6][64];
    __shared__ __align__(16) float adj_s[64];
    __shared__ __align__(16) float hs[16][64];
    __shared__ __align__(16) float ws_s[16][256];

    int t = threadIdx.x;
    int it = blockIdx.x, b = blockIdx.y;
    int i0 = it * 8;
    int rg = t >> 5, cg = t & 31;
    int lane = t & 63, wv = t >> 6;
    int ii_l = lane >> 3, jj_l = lane & 7;

    #pragma unroll
    for (int q = 0; q < 8; ++q) xi_s[q][t] = xi0[(b * 256 + i0 + q) * 256 + t];
    #pragma unroll
    for (int q = 0; q < 6; ++q) wat_s[q][t] = Wat[q * 256 + t];
    ba_s[t] = b_alpha[t];
    float xi1v[8];
    #pragma unroll
    for (int y = 0; y < 8; ++y) xi1v[y] = xi1[(b * 256 + i0 + rg) * 256 + cg * 8 + y];
    float ah1[8] = {};

    for (int jt = 0; jt < 32; ++jt) {
        int j0 = jt * 8;
        __syncthreads();
        #pragma unroll
        for (int q = 0; q < 8; ++q) {
            xj_s[q][t]  = xj0b[(b * 256 + j0 + q) * 256 + t];
            xj1_s[q][t] = xj1b[(b * 256 + j0 + q) * 256 + t];
        }
        for (int e = t; e < 384; e += 256) {
            int ii = e / 48, rem = e % 48;
            int jjp = rem / 6, c = rem % 6;
            rel_s[c][ii * 8 + jjp] = rel[((b * 256 + i0 + ii) * 256 + j0 + jjp) * 6 + c];
        }
        if (t < 64) adj_s[t] = adj2[(b * 256 + i0 + (t >> 3)) * 256 + j0 + (t & 7)];

        float acc[8][8] = {};
        for (int c = 0; c < 16; ++c) {
            __syncthreads();
            #pragma unroll
            for (int p = 0; p < 4; ++p) {
                int klocal = wv + p * 4;
                int kg = c * 16 + klocal;
                float a = ba_s[kg];
                #pragma unroll
                for (int cc = 0; cc < 6; ++cc) a += rel_s[cc][lane] * wat_s[cc][kg];
                float h = xi_s[ii_l][kg] + xj_s[jj_l][kg] + a;
                hs[klocal][lane] = fmaxf(h, 0.f);
            }
            #pragma unroll
            for (int q = 0; q < 4; ++q) {
                int f = q * 256 + t;
                int row = f >> 6, col4 = f & 63;
                *(float4*)&ws_s[row][col4 * 4] =
                    *(const float4*)&w_alpha0[(c * 16 + row) * 256 + col4 * 4];
            }
            __syncthreads();
            #pragma unroll
            for (int kk = 0; kk < 16; ++kk) {
                float4 a0 = *(const float4*)&hs[kk][rg * 8];
                float4 a1 = *(const float4*)&hs[kk][rg * 8 + 4];
                float4 b0 = *(const float4*)&ws_s[kk][cg * 8];
                float4 b1 = *(const float4*)&ws_s[kk][cg * 8 + 4];
                float av[8] = {a0.x, a0.y, a0.z, a0.w, a1.x, a1.y, a1.z, a1.w};
                float bv[8] = {b0.x, b0.y, b0.z, b0.w, b1.x, b1.y, b1.z, b1.w};
                #pragma unroll
                for (int x = 0; x < 8; ++x)
                    #pragma unroll
                    for (int y = 0; y < 8; ++y)
                        acc[x][y] += av[x] * bv[y];
            }
        }
        #pragma unroll
        for (int x = 0; x < 8; ++x) {
            float a2 = adj_s[rg * 8 + x];
            #pragma unroll
            for (int y = 0; y < 8; ++y) {
                float al = fmaxf(acc[x][y], 0.f);
                float h1 = fmaxf(xi1v[y] + xj1_s[x][cg * 8 + y] + al, 0.f);
                ah1[y] += a2 * h1;
            }
        }
    }
    #pragma unroll
    for (int y = 0; y < 8; ++y)
        AH1[(b * 256 + i0 + rg) * 256 + cg * 8 + y] = ah1[y];
}

// ---------------------------------------------------------------------------
extern "C" void kernel_launch(void* const* d_in, const int* in_sizes, int n_in,
                              void* d_out, int out_size, void* d_ws, size_t ws_size,
                              hipStream_t stream)
{
    const float* x        = (const float*)d_in[0];
    const float* rel      = (const float*)d_in[1];
    const float* adj      = (const float*)d_in[2];
    const int*   box_num  = (const int*)d_in[3];
    const float* Wat      = (const float*)d_in[4];
    const float* b_alpha  = (const float*)d_in[5];
    const float* W_proj   = (const float*)d_in[6];
    const float* b_proj   = (const float*)d_in[7];
    const float* learn_w  = (const float*)d_in[8];
    const float* w_alpha0 = (const float*)d_in[9];
    const float* w_vi0    = (const float*)d_in[10];
    const float* w_vj0    = (const float*)d_in[11];
    const float* bias_h0  = (const float*)d_in[12];
    const float* w_node0  = (const float*)d_in[13];
    // d_in[14] = l1_w_alpha (unused: layer-1 new_alpha is discarded)
    const float* w_vi1    = (const float*)d_in[15];
    const float* w_vj1    = (const float*)d_in[16];
    const float* bias_h1  = (const float*)d_in[17];
    const float* w_node1  = (const float*)d_in[18];

    // ---- workspace layout ----
    float* sm    = (float*)d_ws;
    float* adj2  = sm;                 // 262,144
    float* xhat  = adj2  + 262144;     // 131,072
    float* xi0   = xhat  + 131072;     // 262,144
    float* xj0b  = xi0   + 262144;     // 262,144
    float* AH0   = xj0b  + 262144;     // 262,144
    float* x1    = AH0   + 262144;     // 262,144
    float* xi1   = x1    + 262144;     // 262,144
    float* xj1b  = xi1   + 262144;     // 262,144
    float* AH1   = xj1b  + 262144;     // 262,144
    float* rowP1 = AH1   + 262144;     //   1,024
    float* rowP2 = rowP1 + 1024;       //   1,024
    const size_t SMALLS_F = 2230272;   // floats
    const size_t WTP_F    = 65536;     // 256 KB packed hi/lo W
    const size_t PART_F   = 8388608;
    u32*   wTp    = (u32*)(sm + SMALLS_F);
    float* part   = sm + SMALLS_F + WTP_F;
    u32*   alpha1 = (u32*)(sm + SMALLS_F + WTP_F + PART_F);   // bf16-packed, 128 MiB

    const size_t needM = (SMALLS_F + WTP_F + PART_F) * 4ULL + 134217728ULL;  // ~169 MB
    int use_mfma = (ws_size >= needM);

    float* out_x2   = (float*)d_out;
    float* out_soft = out_x2 + 262144;
    float* out_gl   = out_soft + 262144;

    // W prep (independent of everything else) first
    if (use_mfma) wprep<<<32, 256, 0, stream>>>(w_alpha0, wTp);

    // Phase A projections, fused: xhat + xi0 + xj0b (160 live blocks)
    {
        GJob ja{x, W_proj, b_proj, nullptr, xhat, 256, 128, 0};
        GJob jb{x, w_vi0,  nullptr, nullptr, xi0,  256, 256, 0};
        GJob jc{x, w_vj0,  nullptr, bias_h0, xj0b, 256, 256, 0};
        gemm64_multi<<<dim3(16, 4, 3), 256, 0, stream>>>(ja, jb, jc);
    }
    soft_adj_kernel<<<1024, 256, 0, stream>>>(xhat, adj, box_num, learn_w, out_soft, adj2, rowP1, rowP2);
    gl_loss_kernel<<<4, 256, 0, stream>>>(rowP1, rowP2, box_num, out_gl);

    // Layer 0 heavy pass
    if (use_mfma) {
        pass1M<<<dim3(32, 32, 4), 256, 0, stream>>>(rel, Wat, b_alpha, xi0, xj0b, adj2, wTp, alpha1, part);
        reduce_ah<<<1024, 256, 0, stream>>>(part, AH0);
    } else {
        pass1C<<<dim3(32, 4), 256, 0, stream>>>(rel, Wat, b_alpha, xi0, xj0b, adj2, AH0);
    }

    // Layer 0 node update, then fused layer-1 projections
    gemm64<<<dim3(16, 4), 256, 0, stream>>>(AH0, w_node0, nullptr, nullptr, x1, 1024, 256, 256, 1);
    {
        GJob j1a{x1, w_vi1, nullptr, nullptr, xi1,  256, 256, 0};
        GJob j1b{x1, w_vj1, nullptr, bias_h1, xj1b, 256, 256, 0};
        gemm64_multi<<<dim3(16, 4, 2), 256, 0, stream>>>(j1a, j1b, j1b);
    }

    // Layer 1 -> AH1
    if (use_mfma) {
        pass2b<<<1024, 256, 0, stream>>>(alpha1, xi1, xj1b, adj2, AH1);
    } else {
        pass2C<<<dim3(32, 4), 256, 0, stream>>>(rel, Wat, b_alpha, xi0, xj0b, w_alpha0, xi1, xj1b, adj2, AH1);
    }

    // Final node update -> x2
    gemm64<<<dim3(16, 4), 256, 0, stream>>>(AH1, w_node1, nullptr, nullptr, out_x2, 1024, 256, 256, 1);
}

// Round 7
// 358.922 us; speedup vs baseline: 2.1511x; 1.1328x over previous
//
#include <hip/hip_runtime.h>

// Problem constants
#define NB 4
#define NN 256
#define ND 256
#define NL 128
#define NK 256
static constexpr float GAMMA_C = 1e-4f;
static constexpr float ETA_C = 1.0f;

typedef unsigned int u32;
typedef __attribute__((ext_vector_type(8))) short bf16x8;
typedef __attribute__((ext_vector_type(4))) float f32x4;

__device__ __forceinline__ u32 rne1(float x) {            // f32 -> bf16 bits (RNE)
    u32 a = __float_as_uint(x);
    return (a + 0x7FFFu + ((a >> 16) & 1u)) >> 16;
}
__device__ __forceinline__ float bf2f(u32 v) { return __uint_as_float(v << 16); }
__device__ __forceinline__ u32 pk2bf(float lo, float hi) { return rne1(lo) | (rne1(hi) << 16); }

struct GJob {
    const float* A; const float* W; const float* bias; const float* addm;
    float* C; int Kd; int Nc; int relu;
};

// ---------------------------------------------------------------------------
// Generic small GEMM: C[M,Nc] = act(A[M,K] @ W[K,Nc] + bias[col] + addm[row%256,col])
// ---------------------------------------------------------------------------
__device__ __forceinline__ void gemm64_body(
    const float* __restrict__ A, const float* __restrict__ W,
    const float* __restrict__ bias, const float* __restrict__ addm,
    float* __restrict__ C, int Kd, int Nc, int relu_act)
{
    __shared__ __align__(16) float As[16][68];
    __shared__ __align__(16) float Ws[16][64];
    int t = threadIdx.x;
    int r0 = blockIdx.x * 64, c0 = blockIdx.y * 64;
    int ty = t >> 4, tx = t & 15;
    float acc[4][4] = {};
    for (int kc = 0; kc < Kd; kc += 16) {
        __syncthreads();
        #pragma unroll
        for (int q = 0; q < 4; ++q) {
            int f = q * 256 + t;
            int row = f >> 4, kk = f & 15;
            As[kk][row] = A[(r0 + row) * Kd + kc + kk];
        }
        #pragma unroll
        for (int q = 0; q < 4; ++q) {
            int f = q * 256 + t;
            int kk = f >> 6, col = f & 63;
            Ws[kk][col] = W[(kc + kk) * Nc + c0 + col];
        }
        __syncthreads();
        #pragma unroll
        for (int kk = 0; kk < 16; ++kk) {
            float4 av = *(const float4*)&As[kk][ty * 4];
            float4 bv = *(const float4*)&Ws[kk][tx * 4];
            float a[4] = {av.x, av.y, av.z, av.w};
            float b[4] = {bv.x, bv.y, bv.z, bv.w};
            #pragma unroll
            for (int i = 0; i < 4; ++i)
                #pragma unroll
                for (int j = 0; j < 4; ++j)
                    acc[i][j] += a[i] * b[j];
        }
    }
    #pragma unroll
    for (int i = 0; i < 4; ++i) {
        int row = r0 + ty * 4 + i;
        #pragma unroll
        for (int j = 0; j < 4; ++j) {
            int col = c0 + tx * 4 + j;
            float v = acc[i][j];
            if (bias) v += bias[col];
            if (addm) v += addm[(row & 255) * Nc + col];
            if (relu_act) v = fmaxf(v, 0.f);
            C[row * Nc + col] = v;
        }
    }
}

__global__ __launch_bounds__(256) void gemm64(
    const float* __restrict__ A, const float* __restrict__ W,
    const float* __restrict__ bias, const float* __restrict__ addm,
    float* __restrict__ C, int M, int Kd, int Nc, int relu_act)
{
    gemm64_body(A, W, bias, addm, C, Kd, Nc, relu_act);
}

// Fused multi-GEMM: blockIdx.z selects the job
__global__ __launch_bounds__(256) void gemm64_multi(GJob j0, GJob j1, GJob j2)
{
    GJob jb = (blockIdx.z == 0) ? j0 : (blockIdx.z == 1) ? j1 : j2;
    if ((int)blockIdx.y * 64 >= jb.Nc) return;     // uniform per block
    gemm64_body(jb.A, jb.W, jb.bias, jb.addm, jb.C, jb.Kd, jb.Nc, jb.relu);
}

// ---------------------------------------------------------------------------
// Graph learning: per (b,i) row -> soft_adj, adj2, loss partials
// ---------------------------------------------------------------------------
__global__ __launch_bounds__(256) void soft_adj_kernel(
    const float* __restrict__ xhat, const float* __restrict__ adj,
    const int* __restrict__ box_num, const float* __restrict__ learn_w,
    float* __restrict__ soft_out, float* __restrict__ adj2,
    float* __restrict__ rowP1, float* __restrict__ rowP2)
{
    __shared__ __align__(16) float xs[NL];
    __shared__ __align__(16) float lw[NL];
    __shared__ float red[256];
    int bi = blockIdx.x;            // b*256 + i
    int b = bi >> 8, i = bi & 255;
    int j = threadIdx.x;
    if (j < NL) { xs[j] = xhat[bi * NL + j]; lw[j] = learn_w[j]; }
    __syncthreads();
    float sumw = 0.f;
    for (int d = 0; d < NL; ++d) sumw += lw[d];
    float s1 = 0.f, s2 = 0.f;
    const float* xj = &xhat[(b * 256 + j) * NL];
    #pragma unroll 4
    for (int d = 0; d < NL; d += 4) {
        float4 a = *(const float4*)&xs[d];
        float4 bb = *(const float4*)&xj[d];
        float d0 = a.x - bb.x, d1 = a.y - bb.y, d2 = a.z - bb.z, d3 = a.w - bb.w;
        s1 += fabsf(d0) * lw[d] + fabsf(d1) * lw[d + 1] + fabsf(d2) * lw[d + 2] + fabsf(d3) * lw[d + 3];
        s2 += d0 * d0 + d1 * d1 + d2 * d2 + d3 * d3;
    }
    int bn = box_num[b];
    float maskv = (i < bn && j < bn) ? 0.f : -1.f;
    float out = s1 + maskv * sumw;
    out = (out >= 0.f) ? out : 0.01f * out;     // leaky_relu slope 0.01
    float pn = sqrtf(s2 + 1e-12f);
    red[j] = out; __syncthreads();
    for (int s = 128; s > 0; s >>= 1) { if (j < s) red[j] = fmaxf(red[j], red[j + s]); __syncthreads(); }
    float m = red[0]; __syncthreads();
    float aij = adj[bi * 256 + j];
    float e = expf(out - m) * aij;
    red[j] = e; __syncthreads();
    for (int s = 128; s > 0; s >>= 1) { if (j < s) red[j] += red[j + s]; __syncthreads(); }
    float S = red[0]; __syncthreads();
    float soft = e / S + 1e-10f;
    soft_out[bi * 256 + j] = soft;
    adj2[bi * 256 + j] = aij * soft;
    float p1 = expf(soft + ETA_C * pn);
    float p2 = soft * soft;
    red[j] = p1; __syncthreads();
    for (int s = 128; s > 0; s >>= 1) { if (j < s) red[j] += red[j + s]; __syncthreads(); }
    if (j == 0) rowP1[bi] = red[0];
    __syncthreads();
    red[j] = p2; __syncthreads();
    for (int s = 128; s > 0; s >>= 1) { if (j < s) red[j] += red[j + s]; __syncthreads(); }
    if (j == 0) rowP2[bi] = red[0];
}

__global__ __launch_bounds__(256) void gl_loss_kernel(
    const float* __restrict__ rowP1, const float* __restrict__ rowP2,
    const int* __restrict__ box_num, float* __restrict__ out)
{
    __shared__ float r1[256], r2[256];
    int b = blockIdx.x, t = threadIdx.x;
    r1[t] = rowP1[b * 256 + t];
    r2[t] = rowP2[b * 256 + t];
    __syncthreads();
    for (int s = 128; s > 0; s >>= 1) { if (t < s) { r1[t] += r1[t + s]; r2[t] += r2[t + s]; } __syncthreads(); }
    if (t == 0) {
        float bn = (float)box_num[b];
        out[b] = r1[0] / (bn * bn) + GAMMA_C * sqrtf(r2[0]);
    }
}

// ---------------------------------------------------------------------------
// W prep: split w_alpha0 (256x256, k-major) into hi/lo bf16, packed u32 pairs:
//   wTp[hl][c(8)][kgl(4)][n(256)][q(4)], u32 q packs k = c*32+kgl*8+2q, +1
// ---------------------------------------------------------------------------
__global__ __launch_bounds__(256) void wprep(
    const float* __restrict__ w_alpha0, u32* __restrict__ wTp)
{
    int c = blockIdx.x >> 2, kgl = blockIdx.x & 3;
    int n = threadIdx.x;
    #pragma unroll
    for (int q = 0; q < 4; ++q) {
        int k = c * 32 + kgl * 8 + 2 * q;
        float w0 = w_alpha0[k * 256 + n];
        float w1 = w_alpha0[(k + 1) * 256 + n];
        u32 h0 = rne1(w0), h1 = rne1(w1);
        float l0 = w0 - bf2f(h0), l1 = w1 - bf2f(h1);
        wTp[(((0 * 8 + c) * 4 + kgl) * 256 + n) * 4 + q] = h0 | (h1 << 16);
        wTp[(((1 * 8 + c) * 4 + kgl) * 256 + n) * 4 + q] = rne1(l0) | (rne1(l1) << 16);
    }
}

// ---------------------------------------------------------------------------
// Pass 1 (MFMA): per (b, 8i, 8j) tile. H0 on-the-fly (f32) -> hi/lo bf16 in
// LDS; B-fragments read DIRECTLY from global wTp (L1/L2-resident, no LDS
// staging, no prefetch registers). Two barriers per chunk (safe schedule);
// separate epilogue staging buffer (no LDS union).
// LDS 41.2KB -> 3 blocks/CU with launch_bounds(256,3).
// ---------------------------------------------------------------------------
__global__ __launch_bounds__(256, 3) void pass1M(
    const float* __restrict__ rel, const float* __restrict__ Wat,
    const float* __restrict__ b_alpha, const float* __restrict__ xi0,
    const float* __restrict__ xj0b, const float* __restrict__ adj2,
    const u32* __restrict__ wTp,
    u32* __restrict__ alpha1, float* __restrict__ ahpart)
{
    __shared__ __align__(16) float watb_s[256][8];   // {Wat[0..5][k], b_alpha[k], 0}
    __shared__ __align__(16) u32 hsA[2][2][4][64][4];// [db][hl][kgl][m][q]
    __shared__ __align__(16) float st[16][260];      // epilogue staging (own buffer)

    int t = threadIdx.x;
    int jt = blockIdx.x, it = blockIdx.y, b = blockIdx.z;
    int i0 = it * 8, j0 = jt * 8;
    int m = t & 63, wv = t >> 6;       // lane == m; wave id wv
    int ii = m >> 3, jj = m & 7;
    int l4 = m >> 4, l16 = m & 15;

    // block-start staging
    #pragma unroll
    for (int q = 0; q < 8; ++q)
        watb_s[t][q] = (q < 6) ? Wat[q * 256 + t] : (q == 6 ? b_alpha[t] : 0.f);
    float relv2[6];
    #pragma unroll
    for (int c = 0; c < 6; ++c)
        relv2[c] = rel[((b * 256 + i0 + ii) * 256 + j0 + jj) * 6 + c];
    float adjv = adj2[(b * 256 + i0 + ii) * 256 + j0 + jj];
    float* ahbase = &ahpart[(((jt * 4 + b) * 32 + it) * 8 + ii) * 256];
    const float* xirow = &xi0[(b * 256 + i0 + ii) * 256];
    const float* xjrow = &xj0b[(b * 256 + j0 + jj) * 256];

    f32x4 acc[4][4];
    #pragma unroll
    for (int a = 0; a < 4; ++a)
        #pragma unroll
        for (int c = 0; c < 4; ++c)
            acc[a][c] = (f32x4){0.f, 0.f, 0.f, 0.f};

    __syncthreads();   // watb_s ready

    for (int c = 0; c < 8; ++c) {
        int db = c & 1;
        // ---- H0 chunk: thread computes h(m, k) for k = c*32 + wv*8 + 0..7 ----
        int kb = c * 32 + wv * 8;
        float xiarr[8], xjarr[8];
        {
            float4 x0 = *(const float4*)&xirow[kb];
            float4 x1 = *(const float4*)&xirow[kb + 4];
            xiarr[0]=x0.x; xiarr[1]=x0.y; xiarr[2]=x0.z; xiarr[3]=x0.w;
            xiarr[4]=x1.x; xiarr[5]=x1.y; xiarr[6]=x1.z; xiarr[7]=x1.w;
            float4 y0 = *(const float4*)&xjrow[kb];
            float4 y1 = *(const float4*)&xjrow[kb + 4];
            xjarr[0]=y0.x; xjarr[1]=y0.y; xjarr[2]=y0.z; xjarr[3]=y0.w;
            xjarr[4]=y1.x; xjarr[5]=y1.y; xjarr[6]=y1.z; xjarr[7]=y1.w;
        }
        float h[8];
        #pragma unroll
        for (int i = 0; i < 8; ++i) {
            int k = kb + i;
            float4 wa = *(const float4*)&watb_s[k][0];   // uniform-address broadcast
            float4 wc = *(const float4*)&watb_s[k][4];
            float a = relv2[0]*wa.x + relv2[1]*wa.y + relv2[2]*wa.z + relv2[3]*wa.w
                    + relv2[4]*wc.x + relv2[5]*wc.y + wc.z;   // wc.z = b_alpha[k]
            h[i] = fmaxf(xiarr[i] + xjarr[i] + a, 0.f);
        }
        // ---- AH0 partial: butterfly over jj, lane jj keeps element jj ----
        {
            float ahv = 0.f;
            #pragma unroll
            for (int i = 0; i < 8; ++i) {
                float v = adjv * h[i];
                v += __shfl_xor(v, 1);
                v += __shfl_xor(v, 2);
                v += __shfl_xor(v, 4);
                ahv = (jj == i) ? v : ahv;
            }
            ahbase[kb + jj] = ahv;
        }
        // ---- split hi/lo, pack, write to hsA[db] ----
        {
            u32 hi[4], lo[4];
            #pragma unroll
            for (int p = 0; p < 4; ++p) {
                float h0 = h[2*p], h1 = h[2*p+1];
                u32 a0 = rne1(h0), a1 = rne1(h1);
                hi[p] = a0 | (a1 << 16);
                lo[p] = rne1(h0 - bf2f(a0)) | (rne1(h1 - bf2f(a1)) << 16);
            }
            *(uint4*)&hsA[db][0][wv][m][0] = make_uint4(hi[0], hi[1], hi[2], hi[3]);
            *(uint4*)&hsA[db][1][wv][m][0] = make_uint4(lo[0], lo[1], lo[2], lo[3]);
        }
        __syncthreads();   // hsA[db] ready

        // ---- fragments + MFMA: A from LDS, B straight from global (L1/L2) ----
        bf16x8 aH[4], aL[4];
        #pragma unroll
        for (int mt = 0; mt < 4; ++mt) {
            aH[mt] = *(const bf16x8*)&hsA[db][0][l4][mt * 16 + l16][0];
            aL[mt] = *(const bf16x8*)&hsA[db][1][l4][mt * 16 + l16][0];
        }
        const u32* wc0 = &wTp[(c * 4 + l4) * 1024];          // hl=0 chunk base
        const u32* wc1 = &wTp[((8 + c) * 4 + l4) * 1024];    // hl=1 chunk base
        #pragma unroll
        for (int ntl = 0; ntl < 4; ++ntl) {
            int n = (wv * 4 + ntl) * 16 + l16;
            bf16x8 bH = *(const bf16x8*)&wc0[n * 4];
            bf16x8 bL = *(const bf16x8*)&wc1[n * 4];
            #pragma unroll
            for (int mt = 0; mt < 4; ++mt) {
                acc[mt][ntl] = __builtin_amdgcn_mfma_f32_16x16x32_bf16(aH[mt], bH, acc[mt][ntl], 0, 0, 0);
                acc[mt][ntl] = __builtin_amdgcn_mfma_f32_16x16x32_bf16(aH[mt], bL, acc[mt][ntl], 0, 0, 0);
                acc[mt][ntl] = __builtin_amdgcn_mfma_f32_16x16x32_bf16(aL[mt], bH, acc[mt][ntl], 0, 0, 0);
            }
        }
        __syncthreads();   // MFMA fragment reads done before next chunk's writes
    }

    // ---- epilogue: relu + bf16-pack alpha1 via LDS staging, 4 quarter-passes ----
    #pragma unroll
    for (int mt = 0; mt < 4; ++mt) {
        #pragma unroll
        for (int ntl = 0; ntl < 4; ++ntl) {
            int n = (wv * 4 + ntl) * 16 + l16;
            #pragma unroll
            for (int r = 0; r < 4; ++r)
                st[l4 * 4 + r][n] = acc[mt][ntl][r];
        }
        __syncthreads();
        #pragma unroll
        for (int p = 0; p < 2; ++p) {
            int f = p * 256 + t;                     // 0..511
            int row = f >> 5, u8 = f & 31;           // row 0..15, 8 f32 each
            float4 c0 = *(const float4*)&st[row][u8 * 8];
            float4 c1 = *(const float4*)&st[row][u8 * 8 + 4];
            uint4 pk;
            pk.x = pk2bf(fmaxf(c0.x, 0.f), fmaxf(c0.y, 0.f));
            pk.y = pk2bf(fmaxf(c0.z, 0.f), fmaxf(c0.w, 0.f));
            pk.z = pk2bf(fmaxf(c1.x, 0.f), fmaxf(c1.y, 0.f));
            pk.w = pk2bf(fmaxf(c1.z, 0.f), fmaxf(c1.w, 0.f));
            int mg = mt * 16 + row;                  // pair row 0..63
            int iw = mg >> 3, jw = mg & 7;
            *(uint4*)&alpha1[((b * 256 + i0 + iw) * 256 + j0 + jw) * 128 + u8 * 4] = pk;
        }
        __syncthreads();
    }
}

__global__ __launch_bounds__(256) void reduce_ah(
    const float* __restrict__ part, float* __restrict__ AH0)
{
    int bi = blockIdx.x;
    int b = bi >> 8, i = bi & 255;
    int it = i >> 3, ii = i & 7;
    int t = threadIdx.x;
    float s = 0.f;
    for (int jt = 0; jt < 32; ++jt)
        s += part[(((jt * 4 + b) * 32 + it) * 8 + ii) * 256 + t];
    AH0[bi * 256 + t] = s;
}

// ---------------------------------------------------------------------------
// Pass 2: stream bf16 alpha1, accumulate AH1
// ---------------------------------------------------------------------------
__global__ __launch_bounds__(256) void pass2b(
    const u32* __restrict__ alpha1, const float* __restrict__ xi1,
    const float* __restrict__ xj1b, const float* __restrict__ adj2,
    float* __restrict__ AH1)
{
    __shared__ __align__(16) float partial[4][256];
    int bi = blockIdx.x;
    int b = bi >> 8;
    int t = threadIdx.x;
    int wv = t >> 6, lane = t & 63;
    int k4 = lane * 4;
    float4 xi = *(const float4*)&xi1[bi * 256 + k4];
    float4 acc = {0.f, 0.f, 0.f, 0.f};
    size_t base = (size_t)bi * 32768;   // u32 units: 256*128
    const float* a2row = &adj2[bi * 256];
    for (int j = wv; j < 256; j += 4) {
        float a2 = a2row[j];
        float4 xj = *(const float4*)&xj1b[(b * 256 + j) * 256 + k4];
        uint2 q = *(const uint2*)&alpha1[base + j * 128 + (k4 >> 1)];
        float4 al;
        al.x = bf2f(q.x & 0xFFFFu); al.y = bf2f(q.x >> 16);
        al.z = bf2f(q.y & 0xFFFFu); al.w = bf2f(q.y >> 16);
        acc.x += a2 * fmaxf(xi.x + xj.x + al.x, 0.f);
        acc.y += a2 * fmaxf(xi.y + xj.y + al.y, 0.f);
        acc.z += a2 * fmaxf(xi.z + xj.z + al.z, 0.f);
        acc.w += a2 * fmaxf(xi.w + xj.w + al.w, 0.f);
    }
    *(float4*)&partial[wv][k4] = acc;
    __syncthreads();
    if (wv == 0) {
        float4 p0 = *(const float4*)&partial[0][k4];
        float4 p1 = *(const float4*)&partial[1][k4];
        float4 p2 = *(const float4*)&partial[2][k4];
        float4 p3 = *(const float4*)&partial[3][k4];
        float4 o;
        o.x = p0.x + p1.x + p2.x + p3.x;
        o.y = p0.y + p1.y + p2.y + p3.y;
        o.z = p0.z + p1.z + p2.z + p3.z;
        o.w = p0.w + p1.w + p2.w + p3.w;
        *(float4*)&AH1[bi * 256 + k4] = o;
    }
}

// ---------------------------------------------------------------------------
// Tier C fallback kernels (tiny-ws path)
// ---------------------------------------------------------------------------
__global__ __launch_bounds__(256) void pass1C(
    const float* __restrict__ rel, const float* __restrict__ Wat,
    const float* __restrict__ b_alpha, const float* __restrict__ xi0,
    const float* __restrict__ xj0b, const float* __restrict__ adj2,
    float* __restrict__ AH0)
{
    __shared__ float xj_s[16][257];
    __shared__ float rel_s[16 * 48];
    __shared__ float adj_sC[128];
    int t = threadIdx.x;
    int it = blockIdx.x, b = blockIdx.y;
    int i0 = it * 8;
    float xiv[8], watv[6];
    #pragma unroll
    for (int ii = 0; ii < 8; ++ii) xiv[ii] = xi0[(b * 256 + i0 + ii) * 256 + t];
    #pragma unroll
    for (int c = 0; c < 6; ++c) watv[c] = Wat[c * 256 + t];
    float bav = b_alpha[t];
    float ah[8] = {};
    for (int jc = 0; jc < 256; jc += 16) {
        __syncthreads();
        #pragma unroll
        for (int q = 0; q < 16; ++q) xj_s[q][t] = xj0b[(b * 256 + jc + q) * 256 + t];
        for (int e = t; e < 768; e += 256) {
            int jjp = e / 48, r = e % 48;
            rel_s[e] = rel[((b * 256 + i0 + r / 6) * 256 + jc + jjp) * 6 + (r % 6)];
        }
        if (t < 128) adj_sC[t] = adj2[(b * 256 + i0 + (t & 7)) * 256 + jc + (t >> 3)];
        __syncthreads();
        for (int jjp = 0; jjp < 16; ++jjp) {
            float xjv = xj_s[jjp][t];
            #pragma unroll
            for (int ii = 0; ii < 8; ++ii) {
                float a = bav;
                #pragma unroll
                for (int c = 0; c < 6; ++c) a += rel_s[jjp * 48 + ii * 6 + c] * watv[c];
                float h = fmaxf(xiv[ii] + xjv + a, 0.f);
                ah[ii] += adj_sC[jjp * 8 + ii] * h;
            }
        }
    }
    #pragma unroll
    for (int ii = 0; ii < 8; ++ii)
        AH0[(b * 256 + i0 + ii) * 256 + t] = ah[ii];
}

__global__ __launch_bounds__(256) void pass2C(
    const float* __restrict__ rel, const float* __restrict__ Wat,
    const float* __restrict__ b_alpha, const float* __restrict__ xi0,
    const float* __restrict__ xj0b, const float* __restrict__ w_alpha0,
    const float* __restrict__ xi1, const float* __restrict__ xj1b,
    const float* __restrict__ adj2, float* __restrict__ AH1)
{
    __shared__ float xi_s[8][257];
    __shared__ float xj_s[8][257];
    __shared__ float xj1_s[8][257];
    __shared__ __align__(16) float wat_s[6][256];
    __shared__ __align__(16) float ba_s[256];
    __shared__ __align__(16) float rel_s[6][64];
    __shared__ __align__(16) float adj_s[64];
    __shared__ __align__(16) float hs[16][64];
    __shared__ __align__(16) float ws_s[16][256];

    int t = threadIdx.x;
    int it = blockIdx.x, b = blockIdx.y;
    int i0 = it * 8;
    int rg = t >> 5, cg = t & 31;
    int lane = t & 63, wv = t >> 6;
    int ii_l = lane >> 3, jj_l = lane & 7;

    #pragma unroll
    for (int q = 0; q < 8; ++q) xi_s[q][t] = xi0[(b * 256 + i0 + q) * 256 + t];
    #pragma unroll
    for (int q = 0; q < 6; ++q) wat_s[q][t] = Wat[q * 256 + t];
    ba_s[t] = b_alpha[t];
    float xi1v[8];
    #pragma unroll
    for (int y = 0; y < 8; ++y) xi1v[y] = xi1[(b * 256 + i0 + rg) * 256 + cg * 8 + y];
    float ah1[8] = {};

    for (int jt = 0; jt < 32; ++jt) {
        int j0 = jt * 8;
        __syncthreads();
        #pragma unroll
        for (int q = 0; q < 8; ++q) {
            xj_s[q][t]  = xj0b[(b * 256 + j0 + q) * 256 + t];
            xj1_s[q][t] = xj1b[(b * 256 + j0 + q) * 256 + t];
        }
        for (int e = t; e < 384; e += 256) {
            int ii = e / 48, rem = e % 48;
            int jjp = rem / 6, c = rem % 6;
            rel_s[c][ii * 8 + jjp] = rel[((b * 256 + i0 + ii) * 256 + j0 + jjp) * 6 + c];
        }
        if (t < 64) adj_s[t] = adj2[(b * 256 + i0 + (t >> 3)) * 256 + j0 + (t & 7)];

        float acc[8][8] = {};
        for (int c = 0; c < 16; ++c) {
            __syncthreads();
            #pragma unroll
            for (int p = 0; p < 4; ++p) {
                int klocal = wv + p * 4;
                int kg = c * 16 + klocal;
                float a = ba_s[kg];
                #pragma unroll
                for (int cc = 0; cc < 6; ++cc) a += rel_s[cc][lane] * wat_s[cc][kg];
                float h = xi_s[ii_l][kg] + xj_s[jj_l][kg] + a;
                hs[klocal][lane] = fmaxf(h, 0.f);
            }
            #pragma unroll
            for (int q = 0; q < 4; ++q) {
                int f = q * 256 + t;
                int row = f >> 6, col4 = f & 63;
                *(float4*)&ws_s[row][col4 * 4] =
                    *(const float4*)&w_alpha0[(c * 16 + row) * 256 + col4 * 4];
            }
            __syncthreads();
            #pragma unroll
            for (int kk = 0; kk < 16; ++kk) {
                float4 a0 = *(const float4*)&hs[kk][rg * 8];
                float4 a1 = *(const float4*)&hs[kk][rg * 8 + 4];
                float4 b0 = *(const float4*)&ws_s[kk][cg * 8];
                float4 b1 = *(const float4*)&ws_s[kk][cg * 8 + 4];
                float av[8] = {a0.x, a0.y, a0.z, a0.w, a1.x, a1.y, a1.z, a1.w};
                float bv[8] = {b0.x, b0.y, b0.z, b0.w, b1.x, b1.y, b1.z, b1.w};
                #pragma unroll
                for (int x = 0; x < 8; ++x)
                    #pragma unroll
                    for (int y = 0; y < 8; ++y)
                        acc[x][y] += av[x] * bv[y];
            }
        }
        #pragma unroll
        for (int x = 0; x < 8; ++x) {
            float a2 = adj_s[rg * 8 + x];
            #pragma unroll
            for (int y = 0; y < 8; ++y) {
                float al = fmaxf(acc[x][y], 0.f);
                float h1 = fmaxf(xi1v[y] + xj1_s[x][cg * 8 + y] + al, 0.f);
                ah1[y] += a2 * h1;
            }
        }
    }
    #pragma unroll
    for (int y = 0; y < 8; ++y)
        AH1[(b * 256 + i0 + rg) * 256 + cg * 8 + y] = ah1[y];
}

// ---------------------------------------------------------------------------
extern "C" void kernel_launch(void* const* d_in, const int* in_sizes, int n_in,
                              void* d_out, int out_size, void* d_ws, size_t ws_size,
                              hipStream_t stream)
{
    const float* x        = (const float*)d_in[0];
    const float* rel      = (const float*)d_in[1];
    const float* adj      = (const float*)d_in[2];
    const int*   box_num  = (const int*)d_in[3];
    const float* Wat      = (const float*)d_in[4];
    const float* b_alpha  = (const float*)d_in[5];
    const float* W_proj   = (const float*)d_in[6];
    const float* b_proj   = (const float*)d_in[7];
    const float* learn_w  = (const float*)d_in[8];
    const float* w_alpha0 = (const float*)d_in[9];
    const float* w_vi0    = (const float*)d_in[10];
    const float* w_vj0    = (const float*)d_in[11];
    const float* bias_h0  = (const float*)d_in[12];
    const float* w_node0  = (const float*)d_in[13];
    // d_in[14] = l1_w_alpha (unused: layer-1 new_alpha is discarded)
    const float* w_vi1    = (const float*)d_in[15];
    const float* w_vj1    = (const float*)d_in[16];
    const float* bias_h1  = (const float*)d_in[17];
    const float* w_node1  = (const float*)d_in[18];

    // ---- workspace layout ----
    float* sm    = (float*)d_ws;
    float* adj2  = sm;                 // 262,144
    float* xhat  = adj2  + 262144;     // 131,072
    float* xi0   = xhat  + 131072;     // 262,144
    float* xj0b  = xi0   + 262144;     // 262,144
    float* AH0   = xj0b  + 262144;     // 262,144
    float* x1    = AH0   + 262144;     // 262,144
    float* xi1   = x1    + 262144;     // 262,144
    float* xj1b  = xi1   + 262144;     // 262,144
    float* AH1   = xj1b  + 262144;     // 262,144
    float* rowP1 = AH1   + 262144;     //   1,024
    float* rowP2 = rowP1 + 1024;       //   1,024
    const size_t SMALLS_F = 2230272;   // floats
    const size_t WTP_F    = 65536;     // 256 KB packed hi/lo W
    const size_t PART_F   = 8388608;
    u32*   wTp    = (u32*)(sm + SMALLS_F);
    float* part   = sm + SMALLS_F + WTP_F;
    u32*   alpha1 = (u32*)(sm + SMALLS_F + WTP_F + PART_F);   // bf16-packed, 128 MiB

    const size_t needM = (SMALLS_F + WTP_F + PART_F) * 4ULL + 134217728ULL;  // ~169 MB
    int use_mfma = (ws_size >= needM);

    float* out_x2   = (float*)d_out;
    float* out_soft = out_x2 + 262144;
    float* out_gl   = out_soft + 262144;

    // W prep (independent of everything else) first
    if (use_mfma) wprep<<<32, 256, 0, stream>>>(w_alpha0, wTp);

    // Phase A projections, fused: xhat + xi0 + xj0b (160 live blocks)
    {
        GJob ja{x, W_proj, b_proj, nullptr, xhat, 256, 128, 0};
        GJob jb{x, w_vi0,  nullptr, nullptr, xi0,  256, 256, 0};
        GJob jc{x, w_vj0,  nullptr, bias_h0, xj0b, 256, 256, 0};
        gemm64_multi<<<dim3(16, 4, 3), 256, 0, stream>>>(ja, jb, jc);
    }
    soft_adj_kernel<<<1024, 256, 0, stream>>>(xhat, adj, box_num, learn_w, out_soft, adj2, rowP1, rowP2);
    gl_loss_kernel<<<4, 256, 0, stream>>>(rowP1, rowP2, box_num, out_gl);

    // Layer 0 heavy pass
    if (use_mfma) {
        pass1M<<<dim3(32, 32, 4), 256, 0, stream>>>(rel, Wat, b_alpha, xi0, xj0b, adj2, wTp, alpha1, part);
        reduce_ah<<<1024, 256, 0, stream>>>(part, AH0);
    } else {
        pass1C<<<dim3(32, 4), 256, 0, stream>>>(rel, Wat, b_alpha, xi0, xj0b, adj2, AH0);
    }

    // Layer 0 node update, then fused layer-1 projections
    gemm64<<<dim3(16, 4), 256, 0, stream>>>(AH0, w_node0, nullptr, nullptr, x1, 1024, 256, 256, 1);
    {
        GJob j1a{x1, w_vi1, nullptr, nullptr, xi1,  256, 256, 0};
        GJob j1b{x1, w_vj1, nullptr, bias_h1, xj1b, 256, 256, 0};
        gemm64_multi<<<dim3(16, 4, 2), 256, 0, stream>>>(j1a, j1b, j1b);
    }

    // Layer 1 -> AH1
    if (use_mfma) {
        pass2b<<<1024, 256, 0, stream>>>(alpha1, xi1, xj1b, adj2, AH1);
    } else {
        pass2C<<<dim3(32, 4), 256, 0, stream>>>(rel, Wat, b_alpha, xi0, xj0b, w_alpha0, xi1, xj1b, adj2, AH1);
    }

    // Final node update -> x2
    gemm64<<<dim3(16, 4), 256, 0, stream>>>(AH1, w_node1, nullptr, nullptr, out_x2, 1024, 256, 256, 1);
}

// Round 8
// 341.955 us; speedup vs baseline: 2.2578x; 1.0496x over previous
//
#include <hip/hip_runtime.h>
#include <hip/hip_bf16.h>

// Problem constants
#define NB 4
#define NN 256
#define ND 256
#define NL 128
#define NK 256
static constexpr float GAMMA_C = 1e-4f;
static constexpr float ETA_C = 1.0f;

typedef unsigned int u32;
typedef __attribute__((ext_vector_type(8))) short bf16x8;
typedef __attribute__((ext_vector_type(4))) float f32x4;

__device__ __forceinline__ u32 rne1(float x) {            // f32 -> bf16 bits (RNE)
    u32 a = __float_as_uint(x);
    return (a + 0x7FFFu + ((a >> 16) & 1u)) >> 16;
}
__device__ __forceinline__ float bf2f(u32 v) { return __uint_as_float(v << 16); }
// packed f32x2 -> bf16x2 (RNE, same bits as rne1) -- compiler emits v_cvt_pk_bf16_f32
__device__ __forceinline__ u32 pk2(float lo, float hi) {
    union { __hip_bfloat162 h; u32 u; } cv;
    cv.h = __float22bfloat162_rn(make_float2(lo, hi));
    return cv.u;
}

struct GJob {
    const float* A; const float* W; const float* bias; const float* addm;
    float* C; int Kd; int Nc; int relu;
};

// ---------------------------------------------------------------------------
// Generic small GEMM: C[M,Nc] = act(A[M,K] @ W[K,Nc] + bias[col] + addm[row%256,col])
// ---------------------------------------------------------------------------
__device__ __forceinline__ void gemm64_body(
    const float* __restrict__ A, const float* __restrict__ W,
    const float* __restrict__ bias, const float* __restrict__ addm,
    float* __restrict__ C, int Kd, int Nc, int relu_act)
{
    __shared__ __align__(16) float As[16][68];
    __shared__ __align__(16) float Ws[16][64];
    int t = threadIdx.x;
    int r0 = blockIdx.x * 64, c0 = blockIdx.y * 64;
    int ty = t >> 4, tx = t & 15;
    float acc[4][4] = {};
    for (int kc = 0; kc < Kd; kc += 16) {
        __syncthreads();
        #pragma unroll
        for (int q = 0; q < 4; ++q) {
            int f = q * 256 + t;
            int row = f >> 4, kk = f & 15;
            As[kk][row] = A[(r0 + row) * Kd + kc + kk];
        }
        #pragma unroll
        for (int q = 0; q < 4; ++q) {
            int f = q * 256 + t;
            int kk = f >> 6, col = f & 63;
            Ws[kk][col] = W[(kc + kk) * Nc + c0 + col];
        }
        __syncthreads();
        #pragma unroll
        for (int kk = 0; kk < 16; ++kk) {
            float4 av = *(const float4*)&As[kk][ty * 4];
            float4 bv = *(const float4*)&Ws[kk][tx * 4];
            float a[4] = {av.x, av.y, av.z, av.w};
            float b[4] = {bv.x, bv.y, bv.z, bv.w};
            #pragma unroll
            for (int i = 0; i < 4; ++i)
                #pragma unroll
                for (int j = 0; j < 4; ++j)
                    acc[i][j] += a[i] * b[j];
        }
    }
    #pragma unroll
    for (int i = 0; i < 4; ++i) {
        int row = r0 + ty * 4 + i;
        #pragma unroll
        for (int j = 0; j < 4; ++j) {
            int col = c0 + tx * 4 + j;
            float v = acc[i][j];
            if (bias) v += bias[col];
            if (addm) v += addm[(row & 255) * Nc + col];
            if (relu_act) v = fmaxf(v, 0.f);
            C[row * Nc + col] = v;
        }
    }
}

__global__ __launch_bounds__(256) void gemm64(
    const float* __restrict__ A, const float* __restrict__ W,
    const float* __restrict__ bias, const float* __restrict__ addm,
    float* __restrict__ C, int M, int Kd, int Nc, int relu_act)
{
    gemm64_body(A, W, bias, addm, C, Kd, Nc, relu_act);
}

// Fused multi-GEMM: blockIdx.z selects the job
__global__ __launch_bounds__(256) void gemm64_multi(GJob j0, GJob j1, GJob j2)
{
    GJob jb = (blockIdx.z == 0) ? j0 : (blockIdx.z == 1) ? j1 : j2;
    if ((int)blockIdx.y * 64 >= jb.Nc) return;     // uniform per block
    gemm64_body(jb.A, jb.W, jb.bias, jb.addm, jb.C, jb.Kd, jb.Nc, jb.relu);
}

// ---------------------------------------------------------------------------
// Graph learning: per (b,i) row -> soft_adj, adj2, loss partials
// ---------------------------------------------------------------------------
__global__ __launch_bounds__(256) void soft_adj_kernel(
    const float* __restrict__ xhat, const float* __restrict__ adj,
    const int* __restrict__ box_num, const float* __restrict__ learn_w,
    float* __restrict__ soft_out, float* __restrict__ adj2,
    float* __restrict__ rowP1, float* __restrict__ rowP2)
{
    __shared__ __align__(16) float xs[NL];
    __shared__ __align__(16) float lw[NL];
    __shared__ float red[256];
    int bi = blockIdx.x;            // b*256 + i
    int b = bi >> 8, i = bi & 255;
    int j = threadIdx.x;
    if (j < NL) { xs[j] = xhat[bi * NL + j]; lw[j] = learn_w[j]; }
    __syncthreads();
    float sumw = 0.f;
    for (int d = 0; d < NL; ++d) sumw += lw[d];
    float s1 = 0.f, s2 = 0.f;
    const float* xj = &xhat[(b * 256 + j) * NL];
    #pragma unroll 4
    for (int d = 0; d < NL; d += 4) {
        float4 a = *(const float4*)&xs[d];
        float4 bb = *(const float4*)&xj[d];
        float d0 = a.x - bb.x, d1 = a.y - bb.y, d2 = a.z - bb.z, d3 = a.w - bb.w;
        s1 += fabsf(d0) * lw[d] + fabsf(d1) * lw[d + 1] + fabsf(d2) * lw[d + 2] + fabsf(d3) * lw[d + 3];
        s2 += d0 * d0 + d1 * d1 + d2 * d2 + d3 * d3;
    }
    int bn = box_num[b];
    float maskv = (i < bn && j < bn) ? 0.f : -1.f;
    float out = s1 + maskv * sumw;
    out = (out >= 0.f) ? out : 0.01f * out;     // leaky_relu slope 0.01
    float pn = sqrtf(s2 + 1e-12f);
    red[j] = out; __syncthreads();
    for (int s = 128; s > 0; s >>= 1) { if (j < s) red[j] = fmaxf(red[j], red[j + s]); __syncthreads(); }
    float m = red[0]; __syncthreads();
    float aij = adj[bi * 256 + j];
    float e = expf(out - m) * aij;
    red[j] = e; __syncthreads();
    for (int s = 128; s > 0; s >>= 1) { if (j < s) red[j] += red[j + s]; __syncthreads(); }
    float S = red[0]; __syncthreads();
    float soft = e / S + 1e-10f;
    soft_out[bi * 256 + j] = soft;
    adj2[bi * 256 + j] = aij * soft;
    float p1 = expf(soft + ETA_C * pn);
    float p2 = soft * soft;
    red[j] = p1; __syncthreads();
    for (int s = 128; s > 0; s >>= 1) { if (j < s) red[j] += red[j + s]; __syncthreads(); }
    if (j == 0) rowP1[bi] = red[0];
    __syncthreads();
    red[j] = p2; __syncthreads();
    for (int s = 128; s > 0; s >>= 1) { if (j < s) red[j] += red[j + s]; __syncthreads(); }
    if (j == 0) rowP2[bi] = red[0];
}

__global__ __launch_bounds__(256) void gl_loss_kernel(
    const float* __restrict__ rowP1, const float* __restrict__ rowP2,
    const int* __restrict__ box_num, float* __restrict__ out)
{
    __shared__ float r1[256], r2[256];
    int b = blockIdx.x, t = threadIdx.x;
    r1[t] = rowP1[b * 256 + t];
    r2[t] = rowP2[b * 256 + t];
    __syncthreads();
    for (int s = 128; s > 0; s >>= 1) { if (t < s) { r1[t] += r1[t + s]; r2[t] += r2[t + s]; } __syncthreads(); }
    if (t == 0) {
        float bn = (float)box_num[b];
        out[b] = r1[0] / (bn * bn) + GAMMA_C * sqrtf(r2[0]);
    }
}

// ---------------------------------------------------------------------------
// W prep: split w_alpha0 (256x256, k-major) into hi/lo bf16, packed u32 pairs:
//   wTp[hl][c(8)][kgl(4)][n(256)][q(4)], u32 q packs k = c*32+kgl*8+2q, +1
// ---------------------------------------------------------------------------
__global__ __launch_bounds__(256) void wprep(
    const float* __restrict__ w_alpha0, u32* __restrict__ wTp)
{
    int c = blockIdx.x >> 2, kgl = blockIdx.x & 3;
    int n = threadIdx.x;
    #pragma unroll
    for (int q = 0; q < 4; ++q) {
        int k = c * 32 + kgl * 8 + 2 * q;
        float w0 = w_alpha0[k * 256 + n];
        float w1 = w_alpha0[(k + 1) * 256 + n];
        u32 h0 = rne1(w0), h1 = rne1(w1);
        float l0 = w0 - bf2f(h0), l1 = w1 - bf2f(h1);
        wTp[(((0 * 8 + c) * 4 + kgl) * 256 + n) * 4 + q] = h0 | (h1 << 16);
        wTp[(((1 * 8 + c) * 4 + kgl) * 256 + n) * 4 + q] = rne1(l0) | (rne1(l1) << 16);
    }
}

// ---------------------------------------------------------------------------
// Pass 1 (MFMA): per (b, 8i, 8j) tile. H0 on-the-fly (f32) -> hi/lo bf16 in
// LDS; B-fragments read DIRECTLY from global wTp (L1/L2-resident). Two
// barriers per chunk (round-7 proven schedule); cvt_pk-based bf16 packing.
// LDS 41.2KB -> 3 blocks/CU with launch_bounds(256,3).
// ---------------------------------------------------------------------------
__global__ __launch_bounds__(256, 3) void pass1M(
    const float* __restrict__ rel, const float* __restrict__ Wat,
    const float* __restrict__ b_alpha, const float* __restrict__ xi0,
    const float* __restrict__ xj0b, const float* __restrict__ adj2,
    const u32* __restrict__ wTp,
    u32* __restrict__ alpha1, float* __restrict__ ahpart)
{
    __shared__ __align__(16) float watb_s[256][8];   // {Wat[0..5][k], b_alpha[k], 0}
    __shared__ __align__(16) u32 hsA[2][2][4][64][4];// [db][hl][kgl][m][q]
    __shared__ __align__(16) float st[16][260];      // epilogue staging (own buffer)

    int t = threadIdx.x;
    int jt = blockIdx.x, it = blockIdx.y, b = blockIdx.z;
    int i0 = it * 8, j0 = jt * 8;
    int m = t & 63, wv = t >> 6;       // lane == m; wave id wv
    int ii = m >> 3, jj = m & 7;
    int l4 = m >> 4, l16 = m & 15;

    // block-start staging
    #pragma unroll
    for (int q = 0; q < 8; ++q)
        watb_s[t][q] = (q < 6) ? Wat[q * 256 + t] : (q == 6 ? b_alpha[t] : 0.f);
    float relv2[6];
    #pragma unroll
    for (int c = 0; c < 6; ++c)
        relv2[c] = rel[((b * 256 + i0 + ii) * 256 + j0 + jj) * 6 + c];
    float adjv = adj2[(b * 256 + i0 + ii) * 256 + j0 + jj];
    float* ahbase = &ahpart[(((jt * 4 + b) * 32 + it) * 8 + ii) * 256];
    const float* xirow = &xi0[(b * 256 + i0 + ii) * 256];
    const float* xjrow = &xj0b[(b * 256 + j0 + jj) * 256];

    f32x4 acc[4][4];
    #pragma unroll
    for (int a = 0; a < 4; ++a)
        #pragma unroll
        for (int c = 0; c < 4; ++c)
            acc[a][c] = (f32x4){0.f, 0.f, 0.f, 0.f};

    __syncthreads();   // watb_s ready

    for (int c = 0; c < 8; ++c) {
        int db = c & 1;
        // ---- H0 chunk: thread computes h(m, k) for k = c*32 + wv*8 + 0..7 ----
        int kb = c * 32 + wv * 8;
        float xiarr[8], xjarr[8];
        {
            float4 x0 = *(const float4*)&xirow[kb];
            float4 x1 = *(const float4*)&xirow[kb + 4];
            xiarr[0]=x0.x; xiarr[1]=x0.y; xiarr[2]=x0.z; xiarr[3]=x0.w;
            xiarr[4]=x1.x; xiarr[5]=x1.y; xiarr[6]=x1.z; xiarr[7]=x1.w;
            float4 y0 = *(const float4*)&xjrow[kb];
            float4 y1 = *(const float4*)&xjrow[kb + 4];
            xjarr[0]=y0.x; xjarr[1]=y0.y; xjarr[2]=y0.z; xjarr[3]=y0.w;
            xjarr[4]=y1.x; xjarr[5]=y1.y; xjarr[6]=y1.z; xjarr[7]=y1.w;
        }
        float h[8];
        #pragma unroll
        for (int i = 0; i < 8; ++i) {
            int k = kb + i;
            float4 wa = *(const float4*)&watb_s[k][0];   // uniform-address broadcast
            float4 wc = *(const float4*)&watb_s[k][4];
            float a = relv2[0]*wa.x + relv2[1]*wa.y + relv2[2]*wa.z + relv2[3]*wa.w
                    + relv2[4]*wc.x + relv2[5]*wc.y + wc.z;   // wc.z = b_alpha[k]
            h[i] = fmaxf(xiarr[i] + xjarr[i] + a, 0.f);
        }
        // ---- AH0 partial: butterfly over jj, lane jj keeps element jj ----
        {
            float ahv = 0.f;
            #pragma unroll
            for (int i = 0; i < 8; ++i) {
                float v = adjv * h[i];
                v += __shfl_xor(v, 1);
                v += __shfl_xor(v, 2);
                v += __shfl_xor(v, 4);
                ahv = (jj == i) ? v : ahv;
            }
            ahbase[kb + jj] = ahv;
        }
        // ---- split hi/lo via cvt_pk, write to hsA[db] ----
        {
            u32 hi[4], lo[4];
            #pragma unroll
            for (int p = 0; p < 4; ++p) {
                float h0 = h[2*p], h1 = h[2*p+1];
                u32 hp = pk2(h0, h1);
                float b0 = __uint_as_float(hp << 16);
                float b1 = __uint_as_float(hp & 0xFFFF0000u);
                hi[p] = hp;
                lo[p] = pk2(h0 - b0, h1 - b1);
            }
            *(uint4*)&hsA[db][0][wv][m][0] = make_uint4(hi[0], hi[1], hi[2], hi[3]);
            *(uint4*)&hsA[db][1][wv][m][0] = make_uint4(lo[0], lo[1], lo[2], lo[3]);
        }
        __syncthreads();   // hsA[db] ready

        // ---- fragments + MFMA: A from LDS, B straight from global (L1/L2) ----
        bf16x8 aH[4], aL[4];
        #pragma unroll
        for (int mt = 0; mt < 4; ++mt) {
            aH[mt] = *(const bf16x8*)&hsA[db][0][l4][mt * 16 + l16][0];
            aL[mt] = *(const bf16x8*)&hsA[db][1][l4][mt * 16 + l16][0];
        }
        const u32* wc0 = &wTp[(c * 4 + l4) * 1024];          // hl=0 chunk base
        const u32* wc1 = &wTp[((8 + c) * 4 + l4) * 1024];    // hl=1 chunk base
        #pragma unroll
        for (int ntl = 0; ntl < 4; ++ntl) {
            int n = (wv * 4 + ntl) * 16 + l16;
            bf16x8 bH = *(const bf16x8*)&wc0[n * 4];
            bf16x8 bL = *(const bf16x8*)&wc1[n * 4];
            #pragma unroll
            for (int mt = 0; mt < 4; ++mt) {
                acc[mt][ntl] = __builtin_amdgcn_mfma_f32_16x16x32_bf16(aH[mt], bH, acc[mt][ntl], 0, 0, 0);
                acc[mt][ntl] = __builtin_amdgcn_mfma_f32_16x16x32_bf16(aH[mt], bL, acc[mt][ntl], 0, 0, 0);
                acc[mt][ntl] = __builtin_amdgcn_mfma_f32_16x16x32_bf16(aL[mt], bH, acc[mt][ntl], 0, 0, 0);
            }
        }
        __syncthreads();   // MFMA fragment reads done before next chunk's writes
    }

    // ---- epilogue: relu + bf16-pack alpha1 via LDS staging, 4 quarter-passes ----
    #pragma unroll
    for (int mt = 0; mt < 4; ++mt) {
        #pragma unroll
        for (int ntl = 0; ntl < 4; ++ntl) {
            int n = (wv * 4 + ntl) * 16 + l16;
            #pragma unroll
            for (int r = 0; r < 4; ++r)
                st[l4 * 4 + r][n] = acc[mt][ntl][r];
        }
        __syncthreads();
        #pragma unroll
        for (int p = 0; p < 2; ++p) {
            int f = p * 256 + t;                     // 0..511
            int row = f >> 5, u8 = f & 31;           // row 0..15, 8 f32 each
            float4 c0 = *(const float4*)&st[row][u8 * 8];
            float4 c1 = *(const float4*)&st[row][u8 * 8 + 4];
            uint4 pk;
            pk.x = pk2(fmaxf(c0.x, 0.f), fmaxf(c0.y, 0.f));
            pk.y = pk2(fmaxf(c0.z, 0.f), fmaxf(c0.w, 0.f));
            pk.z = pk2(fmaxf(c1.x, 0.f), fmaxf(c1.y, 0.f));
            pk.w = pk2(fmaxf(c1.z, 0.f), fmaxf(c1.w, 0.f));
            int mg = mt * 16 + row;                  // pair row 0..63
            int iw = mg >> 3, jw = mg & 7;
            *(uint4*)&alpha1[((b * 256 + i0 + iw) * 256 + j0 + jw) * 128 + u8 * 4] = pk;
        }
        __syncthreads();
    }
}

// ---------------------------------------------------------------------------
// post0: per (b,i) row. Fuses: reduce_ah -> x1 = relu(AH0 @ w_node0) ->
// xi1 = x1 @ w_vi1, xj1b = x1 @ w_vj1 + bias_h1[i]. Weights are L2-resident.
// Removes 3 kernel launches + AH0/x1 HBM round-trips.
// ---------------------------------------------------------------------------
__global__ __launch_bounds__(256) void post0(
    const float* __restrict__ part, const float* __restrict__ w_node0,
    const float* __restrict__ w_vi1, const float* __restrict__ w_vj1,
    const float* __restrict__ bias_h1,
    float* __restrict__ xi1, float* __restrict__ xj1b)
{
    __shared__ __align__(16) float ah_s[256];
    __shared__ __align__(16) float x1_s[256];
    int bi = blockIdx.x;
    int b = bi >> 8, i = bi & 255;
    int it = i >> 3, ii = i & 7;
    int t = threadIdx.x;
    // reduce AH0 partials over jt
    float s = 0.f;
    #pragma unroll 4
    for (int jt = 0; jt < 32; ++jt)
        s += part[(((jt * 4 + b) * 32 + it) * 8 + ii) * 256 + t];
    ah_s[t] = s;
    __syncthreads();
    // x1[t] = relu(sum_k AH0[k] * w_node0[k][t])
    float a0 = 0.f;
    #pragma unroll 8
    for (int k = 0; k < 256; ++k)
        a0 += ah_s[k] * w_node0[k * 256 + t];
    x1_s[t] = fmaxf(a0, 0.f);
    __syncthreads();
    // xi1[t] = sum_k x1[k]*w_vi1[k][t];  xj1b[t] = sum_k x1[k]*w_vj1[k][t] + bias_h1[i][t]
    float a1 = 0.f, a2 = 0.f;
    #pragma unroll 8
    for (int k = 0; k < 256; ++k) {
        float xv = x1_s[k];
        a1 += xv * w_vi1[k * 256 + t];
        a2 += xv * w_vj1[k * 256 + t];
    }
    xi1[bi * 256 + t] = a1;
    xj1b[bi * 256 + t] = a2 + bias_h1[i * 256 + t];
}

// ---------------------------------------------------------------------------
// pass2x: stream bf16 alpha1, accumulate AH1 row in LDS, then fused final
// node update: x2 = relu(AH1 @ w_node1). AH1 never touches HBM.
// ---------------------------------------------------------------------------
__global__ __launch_bounds__(256) void pass2x(
    const u32* __restrict__ alpha1, const float* __restrict__ xi1,
    const float* __restrict__ xj1b, const float* __restrict__ adj2,
    const float* __restrict__ w_node1, float* __restrict__ x2)
{
    __shared__ __align__(16) float partial[4][256];
    __shared__ __align__(16) float ah1_s[256];
    int bi = blockIdx.x;
    int b = bi >> 8;
    int t = threadIdx.x;
    int wv = t >> 6, lane = t & 63;
    int k4 = lane * 4;
    float4 xi = *(const float4*)&xi1[bi * 256 + k4];
    float4 acc = {0.f, 0.f, 0.f, 0.f};
    size_t base = (size_t)bi * 32768;   // u32 units: 256*128
    const float* a2row = &adj2[bi * 256];
    for (int j = wv; j < 256; j += 4) {
        float a2 = a2row[j];
        float4 xj = *(const float4*)&xj1b[(b * 256 + j) * 256 + k4];
        uint2 q = *(const uint2*)&alpha1[base + j * 128 + (k4 >> 1)];
        float4 al;
        al.x = bf2f(q.x & 0xFFFFu); al.y = bf2f(q.x >> 16);
        al.z = bf2f(q.y & 0xFFFFu); al.w = bf2f(q.y >> 16);
        acc.x += a2 * fmaxf(xi.x + xj.x + al.x, 0.f);
        acc.y += a2 * fmaxf(xi.y + xj.y + al.y, 0.f);
        acc.z += a2 * fmaxf(xi.z + xj.z + al.z, 0.f);
        acc.w += a2 * fmaxf(xi.w + xj.w + al.w, 0.f);
    }
    *(float4*)&partial[wv][k4] = acc;
    __syncthreads();
    ah1_s[t] = partial[0][t] + partial[1][t] + partial[2][t] + partial[3][t];
    __syncthreads();
    // x2[t] = relu(sum_k AH1[k] * w_node1[k][t])
    float a0 = 0.f;
    #pragma unroll 8
    for (int k = 0; k < 256; ++k)
        a0 += ah1_s[k] * w_node1[k * 256 + t];
    x2[bi * 256 + t] = fmaxf(a0, 0.f);
}

// ---------------------------------------------------------------------------
// Tier C fallback kernels (tiny-ws path)
// ---------------------------------------------------------------------------
__global__ __launch_bounds__(256) void pass1C(
    const float* __restrict__ rel, const float* __restrict__ Wat,
    const float* __restrict__ b_alpha, const float* __restrict__ xi0,
    const float* __restrict__ xj0b, const float* __restrict__ adj2,
    float* __restrict__ AH0)
{
    __shared__ float xj_s[16][257];
    __shared__ float rel_s[16 * 48];
    __shared__ float adj_sC[128];
    int t = threadIdx.x;
    int it = blockIdx.x, b = blockIdx.y;
    int i0 = it * 8;
    float xiv[8], watv[6];
    #pragma unroll
    for (int ii = 0; ii < 8; ++ii) xiv[ii] = xi0[(b * 256 + i0 + ii) * 256 + t];
    #pragma unroll
    for (int c = 0; c < 6; ++c) watv[c] = Wat[c * 256 + t];
    float bav = b_alpha[t];
    float ah[8] = {};
    for (int jc = 0; jc < 256; jc += 16) {
        __syncthreads();
        #pragma unroll
        for (int q = 0; q < 16; ++q) xj_s[q][t] = xj0b[(b * 256 + jc + q) * 256 + t];
        for (int e = t; e < 768; e += 256) {
            int jjp = e / 48, r = e % 48;
            rel_s[e] = rel[((b * 256 + i0 + r / 6) * 256 + jc + jjp) * 6 + (r % 6)];
        }
        if (t < 128) adj_sC[t] = adj2[(b * 256 + i0 + (t & 7)) * 256 + jc + (t >> 3)];
        __syncthreads();
        for (int jjp = 0; jjp < 16; ++jjp) {
            float xjv = xj_s[jjp][t];
            #pragma unroll
            for (int ii = 0; ii < 8; ++ii) {
                float a = bav;
                #pragma unroll
                for (int c = 0; c < 6; ++c) a += rel_s[jjp * 48 + ii * 6 + c] * watv[c];
                float h = fmaxf(xiv[ii] + xjv + a, 0.f);
                ah[ii] += adj_sC[jjp * 8 + ii] * h;
            }
        }
    }
    #pragma unroll
    for (int ii = 0; ii < 8; ++ii)
        AH0[(b * 256 + i0 + ii) * 256 + t] = ah[ii];
}

__global__ __launch_bounds__(256) void pass2C(
    const float* __restrict__ rel, const float* __restrict__ Wat,
    const float* __restrict__ b_alpha, const float* __restrict__ xi0,
    const float* __restrict__ xj0b, const float* __restrict__ w_alpha0,
    const float* __restrict__ xi1, const float* __restrict__ xj1b,
    const float* __restrict__ adj2, float* __restrict__ AH1)
{
    __shared__ float xi_s[8][257];
    __shared__ float xj_s[8][257];
    __shared__ float xj1_s[8][257];
    __shared__ __align__(16) float wat_s[6][256];
    __shared__ __align__(16) float ba_s[256];
    __shared__ __align__(16) float rel_s[6][64];
    __shared__ __align__(16) float adj_s[64];
    __shared__ __align__(16) float hs[16][64];
    __shared__ __align__(16) float ws_s[16][256];

    int t = threadIdx.x;
    int it = blockIdx.x, b = blockIdx.y;
    int i0 = it * 8;
    int rg = t >> 5, cg = t & 31;
    int lane = t & 63, wv = t >> 6;
    int ii_l = lane >> 3, jj_l = lane & 7;

    #pragma unroll
    for (int q = 0; q < 8; ++q) xi_s[q][t] = xi0[(b * 256 + i0 + q) * 256 + t];
    #pragma unroll
    for (int q = 0; q < 6; ++q) wat_s[q][t] = Wat[q * 256 + t];
    ba_s[t] = b_alpha[t];
    float xi1v[8];
    #pragma unroll
    for (int y = 0; y < 8; ++y) xi1v[y] = xi1[(b * 256 + i0 + rg) * 256 + cg * 8 + y];
    float ah1[8] = {};

    for (int jt = 0; jt < 32; ++jt) {
        int j0 = jt * 8;
        __syncthreads();
        #pragma unroll
        for (int q = 0; q < 8; ++q) {
            xj_s[q][t]  = xj0b[(b * 256 + j0 + q) * 256 + t];
            xj1_s[q][t] = xj1b[(b * 256 + j0 + q) * 256 + t];
        }
        for (int e = t; e < 384; e += 256) {
            int ii = e / 48, rem = e % 48;
            int jjp = rem / 6, c = rem % 6;
            rel_s[c][ii * 8 + jjp] = rel[((b * 256 + i0 + ii) * 256 + j0 + jjp) * 6 + c];
        }
        if (t < 64) adj_s[t] = adj2[(b * 256 + i0 + (t >> 3)) * 256 + j0 + (t & 7)];

        float acc[8][8] = {};
        for (int c = 0; c < 16; ++c) {
            __syncthreads();
            #pragma unroll
            for (int p = 0; p < 4; ++p) {
                int klocal = wv + p * 4;
                int kg = c * 16 + klocal;
                float a = ba_s[kg];
                #pragma unroll
                for (int cc = 0; cc < 6; ++cc) a += rel_s[cc][lane] * wat_s[cc][kg];
                float h = xi_s[ii_l][kg] + xj_s[jj_l][kg] + a;
                hs[klocal][lane] = fmaxf(h, 0.f);
            }
            #pragma unroll
            for (int q = 0; q < 4; ++q) {
                int f = q * 256 + t;
                int row = f >> 6, col4 = f & 63;
                *(float4*)&ws_s[row][col4 * 4] =
                    *(const float4*)&w_alpha0[(c * 16 + row) * 256 + col4 * 4];
            }
            __syncthreads();
            #pragma unroll
            for (int kk = 0; kk < 16; ++kk) {
                float4 a0 = *(const float4*)&hs[kk][rg * 8];
                float4 a1 = *(const float4*)&hs[kk][rg * 8 + 4];
                float4 b0 = *(const float4*)&ws_s[kk][cg * 8];
                float4 b1 = *(const float4*)&ws_s[kk][cg * 8 + 4];
                float av[8] = {a0.x, a0.y, a0.z, a0.w, a1.x, a1.y, a1.z, a1.w};
                float bv[8] = {b0.x, b0.y, b0.z, b0.w, b1.x, b1.y, b1.z, b1.w};
                #pragma unroll
                for (int x = 0; x < 8; ++x)
                    #pragma unroll
                    for (int y = 0; y < 8; ++y)
                        acc[x][y] += av[x] * bv[y];
            }
        }
        #pragma unroll
        for (int x = 0; x < 8; ++x) {
            float a2 = adj_s[rg * 8 + x];
            #pragma unroll
            for (int y = 0; y < 8; ++y) {
                float al = fmaxf(acc[x][y], 0.f);
                float h1 = fmaxf(xi1v[y] + xj1_s[x][cg * 8 + y] + al, 0.f);
                ah1[y] += a2 * h1;
            }
        }
    }
    #pragma unroll
    for (int y = 0; y < 8; ++y)
        AH1[(b * 256 + i0 + rg) * 256 + cg * 8 + y] = ah1[y];
}

// ---------------------------------------------------------------------------
extern "C" void kernel_launch(void* const* d_in, const int* in_sizes, int n_in,
                              void* d_out, int out_size, void* d_ws, size_t ws_size,
                              hipStream_t stream)
{
    const float* x        = (const float*)d_in[0];
    const float* rel      = (const float*)d_in[1];
    const float* adj      = (const float*)d_in[2];
    const int*   box_num  = (const int*)d_in[3];
    const float* Wat      = (const float*)d_in[4];
    const float* b_alpha  = (const float*)d_in[5];
    const float* W_proj   = (const float*)d_in[6];
    const float* b_proj   = (const float*)d_in[7];
    const float* learn_w  = (const float*)d_in[8];
    const float* w_alpha0 = (const float*)d_in[9];
    const float* w_vi0    = (const float*)d_in[10];
    const float* w_vj0    = (const float*)d_in[11];
    const float* bias_h0  = (const float*)d_in[12];
    const float* w_node0  = (const float*)d_in[13];
    // d_in[14] = l1_w_alpha (unused: layer-1 new_alpha is discarded)
    const float* w_vi1    = (const float*)d_in[15];
    const float* w_vj1    = (const float*)d_in[16];
    const float* bias_h1  = (const float*)d_in[17];
    const float* w_node1  = (const float*)d_in[18];

    // ---- workspace layout ----
    float* sm    = (float*)d_ws;
    float* adj2  = sm;                 // 262,144
    float* xhat  = adj2  + 262144;     // 131,072
    float* xi0   = xhat  + 131072;     // 262,144
    float* xj0b  = xi0   + 262144;     // 262,144
    float* AH0   = xj0b  + 262144;     // 262,144 (fallback path only)
    float* x1    = AH0   + 262144;     // 262,144 (fallback path only)
    float* xi1   = x1    + 262144;     // 262,144
    float* xj1b  = xi1   + 262144;     // 262,144
    float* AH1   = xj1b  + 262144;     // 262,144 (fallback path only)
    float* rowP1 = AH1   + 262144;     //   1,024
    float* rowP2 = rowP1 + 1024;       //   1,024
    const size_t SMALLS_F = 2230272;   // floats
    const size_t WTP_F    = 65536;     // 256 KB packed hi/lo W
    const size_t PART_F   = 8388608;
    u32*   wTp    = (u32*)(sm + SMALLS_F);
    float* part   = sm + SMALLS_F + WTP_F;
    u32*   alpha1 = (u32*)(sm + SMALLS_F + WTP_F + PART_F);   // bf16-packed, 128 MiB

    const size_t needM = (SMALLS_F + WTP_F + PART_F) * 4ULL + 134217728ULL;  // ~169 MB
    int use_mfma = (ws_size >= needM);

    float* out_x2   = (float*)d_out;
    float* out_soft = out_x2 + 262144;
    float* out_gl   = out_soft + 262144;

    // W prep (independent of everything else) first
    if (use_mfma) wprep<<<32, 256, 0, stream>>>(w_alpha0, wTp);

    // Phase A projections, fused: xhat + xi0 + xj0b
    {
        GJob ja{x, W_proj, b_proj, nullptr, xhat, 256, 128, 0};
        GJob jb{x, w_vi0,  nullptr, nullptr, xi0,  256, 256, 0};
        GJob jc{x, w_vj0,  nullptr, bias_h0, xj0b, 256, 256, 0};
        gemm64_multi<<<dim3(16, 4, 3), 256, 0, stream>>>(ja, jb, jc);
    }
    soft_adj_kernel<<<1024, 256, 0, stream>>>(xhat, adj, box_num, learn_w, out_soft, adj2, rowP1, rowP2);
    gl_loss_kernel<<<4, 256, 0, stream>>>(rowP1, rowP2, box_num, out_gl);

    if (use_mfma) {
        // Layer 0 heavy pass -> alpha1 (bf16) + AH0 partials
        pass1M<<<dim3(32, 32, 4), 256, 0, stream>>>(rel, Wat, b_alpha, xi0, xj0b, adj2, wTp, alpha1, part);
        // Fused: reduce AH0 -> x1 -> xi1/xj1b (one launch)
        post0<<<1024, 256, 0, stream>>>(part, w_node0, w_vi1, w_vj1, bias_h1, xi1, xj1b);
        // Layer 1 + fused final node update -> x2
        pass2x<<<1024, 256, 0, stream>>>(alpha1, xi1, xj1b, adj2, w_node1, out_x2);
    } else {
        pass1C<<<dim3(32, 4), 256, 0, stream>>>(rel, Wat, b_alpha, xi0, xj0b, adj2, AH0);
        gemm64<<<dim3(16, 4), 256, 0, stream>>>(AH0, w_node0, nullptr, nullptr, x1, 1024, 256, 256, 1);
        {
            GJob j1a{x1, w_vi1, nullptr, nullptr, xi1,  256, 256, 0};
            GJob j1b{x1, w_vj1, nullptr, bias_h1, xj1b, 256, 256, 0};
            gemm64_multi<<<dim3(16, 4, 2), 256, 0, stream>>>(j1a, j1b, j1b);
        }
        pass2C<<<dim3(32, 4), 256, 0, stream>>>(rel, Wat, b_alpha, xi0, xj0b, w_alpha0, xi1, xj1b, adj2, AH1);
        gemm64<<<dim3(16, 4), 256, 0, stream>>>(AH1, w_node1, nullptr, nullptr, out_x2, 1024, 256, 256, 1);
    }
}